// Round 1
// baseline (91.173 us; speedup 1.0000x reference)
//
#include <hip/hip_runtime.h>

// FullAttention_Spatial: N=4, L=S=1024, H=16, E=D=64, NUM_POS=2, fp32 in/out.
//
// score = temp*(QK + attn_mask[l,s] + klm[n,s]) + pos_table[pos[n,l,s]][h]
// pos in {0,1} => bias = T0[h] + bit*(T1[h]-T0[h]); T0 cancels in softmax.
// All softmax math in log2 domain (temp2 = temp*log2e, delta2 = dT*log2e).
//
// Prepass 1: pack pos bits (ballot)            -> ws[0.5 MB]
// Prepass 2: K fp32 [n][s][h][e] -> bf16 [n][h][s][e], 16B blocks ^= (s&7)
// Prepass 3: V fp32 [n][s][h][d] -> bf16 [n][h][d][s], per-64s-seg blocks ^= (d&7)
// Main: flash attention, mfma_f32_16x16x32_bf16, swapped QK^T (S^T layout),
//       K/V tiles staged with global_load_lds (16B), O^T accumulated, /l at end.

typedef __attribute__((ext_vector_type(8))) __bf16 bf16x8;
typedef __attribute__((ext_vector_type(4))) float f32x4;
typedef __attribute__((ext_vector_type(4))) unsigned int u32x4;

#define LG2E 1.4426950408889634f

static __device__ __forceinline__ unsigned short f2bf(float x) {
  unsigned int u = __builtin_bit_cast(unsigned int, x);
  u += 0x7FFFu + ((u >> 16) & 1u);
  return (unsigned short)(u >> 16);
}
static __device__ __forceinline__ float bf2f(unsigned short h) {
  return __builtin_bit_cast(float, ((unsigned int)h) << 16);
}
static __device__ __forceinline__ void gload16(const void* g, void* l) {
  __builtin_amdgcn_global_load_lds((const __attribute__((address_space(1))) void*)g,
                                   (__attribute__((address_space(3))) void*)l, 16, 0, 0);
}

// ---------------- prepass 1: pack pos bits ----------------
__global__ __launch_bounds__(256) void k_pack_pos(const int* __restrict__ pos,
                                                  unsigned int* __restrict__ out) {
  int gi = blockIdx.x * 256 + threadIdx.x;
  int v = pos[gi];
  unsigned long long m = __ballot(v & 1);
  int lane = threadIdx.x & 63;
  if (lane == 0) out[gi >> 5] = (unsigned int)m;
  else if (lane == 32) out[gi >> 5] = (unsigned int)(m >> 32);
}

// ---------------- prepass 2: K relayout ----------------
// thread = (n, s, h); read 64 fp32, write 64 bf16 swizzled.
__global__ __launch_bounds__(256) void k_prep_k(const float* __restrict__ K,
                                                unsigned short* __restrict__ Kp) {
  int idx = blockIdx.x * 256 + threadIdx.x;   // ((n*1024+s)*16+h)
  int n = idx >> 14, s = (idx >> 4) & 1023, h = idx & 15;
  const float* src = K + idx * 64;
  unsigned short row[64];
#pragma unroll
  for (int j = 0; j < 16; ++j) {
    float4 v = *(const float4*)(src + j * 4);
    row[j*4+0] = f2bf(v.x); row[j*4+1] = f2bf(v.y);
    row[j*4+2] = f2bf(v.z); row[j*4+3] = f2bf(v.w);
  }
  unsigned short* dst = Kp + ((n * 16 + h) * 1024 + s) * 64;
#pragma unroll
  for (int b = 0; b < 8; ++b) {
    int pb = b ^ (s & 7);
    *(u32x4*)(dst + pb * 8) = *(const u32x4*)(&row[b * 8]);
  }
}

// ---------------- prepass 3: V transpose ----------------
// block = (n, h, t): 64s x 64d tile, transpose via LDS.
__global__ __launch_bounds__(256) void k_prep_v(const float* __restrict__ V,
                                                unsigned short* __restrict__ Vt) {
  __shared__ float ld[64][65];
  int bid = blockIdx.x;
  int t = bid & 15, h = (bid >> 4) & 15, n = bid >> 8;
  int tid = threadIdx.x;
  {
    int s = tid >> 2, dq = (tid & 3) * 16;
    const float* src = V + ((n * 1024 + t * 64 + s) * 16 + h) * 64 + dq;
#pragma unroll
    for (int j = 0; j < 4; ++j) {
      float4 v = *(const float4*)(src + j * 4);
      ld[s][dq + j*4 + 0] = v.x; ld[s][dq + j*4 + 1] = v.y;
      ld[s][dq + j*4 + 2] = v.z; ld[s][dq + j*4 + 3] = v.w;
    }
  }
  __syncthreads();
  {
    int d = tid >> 2, sq = (tid & 3) * 16;
    unsigned short vals[16];
#pragma unroll
    for (int k = 0; k < 16; ++k) vals[k] = f2bf(ld[sq + k][d]);
    unsigned short* dst = Vt + ((n * 16 + h) * 64 + d) * 1024 + t * 64;
#pragma unroll
    for (int cb = 0; cb < 2; ++cb) {
      int blk = (sq >> 3) + cb;          // inner-s 16B block (0..7)
      int pb = blk ^ (d & 7);
      *(u32x4*)(dst + pb * 8) = *(const u32x4*)(&vals[cb * 8]);
    }
  }
}

// ---------------- main flash-attention kernel ----------------
// grid 1024 = (lblk<<6) | (h<<2) | n ; 4 waves x 16 q-rows.
__global__ __launch_bounds__(256, 4) void k_attn(
    const float* __restrict__ Q, const float* __restrict__ mask,
    const float* __restrict__ klm, const float* __restrict__ ptab,
    const unsigned int* __restrict__ pospk,
    const unsigned short* __restrict__ Kp, const unsigned short* __restrict__ Vt,
    float* __restrict__ out) {
  __shared__ __align__(16) unsigned short Kt[4096];    // [64 s][64 e] swizzled
  __shared__ __align__(16) unsigned short Vts[4096];   // [64 d][64 s] swizzled
  __shared__ __align__(16) unsigned short Mz[64 * 66]; // [s][l] (mask+klm)*temp2 bf16
  __shared__ __align__(16) unsigned int Pb[4][512];    // per-wave P^T, swizzled

  int bid = blockIdx.x;
  int n = bid & 3, h = (bid >> 2) & 15, lblk = bid >> 6;
  int tid = threadIdx.x;
  int w = tid >> 6, lane = tid & 63;
  int g = lane >> 4, c = lane & 15;
  int l = lblk * 64 + w * 16 + c;      // this lane's q-row (global)

  // Q fragments (B-operand of swapped QK^T): lane holds Q[l][e=ech*32+8g..+7]
  const float* qrow = Q + ((n * 1024 + l) * 16 + h) * 64;
  bf16x8 qf[2];
#pragma unroll
  for (int e = 0; e < 2; ++e) {
    float4 a = *(const float4*)(qrow + e * 32 + g * 8);
    float4 b = *(const float4*)(qrow + e * 32 + g * 8 + 4);
    u32x4 pk;
    pk[0] = (unsigned)f2bf(a.x) | ((unsigned)f2bf(a.y) << 16);
    pk[1] = (unsigned)f2bf(a.z) | ((unsigned)f2bf(a.w) << 16);
    pk[2] = (unsigned)f2bf(b.x) | ((unsigned)f2bf(b.y) << 16);
    pk[3] = (unsigned)f2bf(b.z) | ((unsigned)f2bf(b.w) << 16);
    qf[e] = __builtin_bit_cast(bf16x8, pk);
  }
  const float temp2 = 0.125f * LG2E;
  const float delta2 = (ptab[16 + h] - ptab[h]) * LG2E;

  float mrun = -1e30f, lrun = 0.f;
  f32x4 Oc[4] = {{0,0,0,0},{0,0,0,0},{0,0,0,0},{0,0,0,0}};

  const unsigned short* KpB = Kp + (n * 16 + h) * (1024 * 64);
  const unsigned short* VtB = Vt + (n * 16 + h) * (64 * 1024);
  const int posbase = (n * 1024 + l) * 32;

  for (int t = 0; t < 16; ++t) {
    __syncthreads();
    // ---- stage K & V tiles: global_load_lds, 16B/lane, 2 calls/wave each ----
#pragma unroll
    for (int j = 0; j < 2; ++j) {
      gload16(KpB + t * 4096 + w * 1024 + j * 512 + lane * 8, &Kt[w * 1024 + j * 512]);
      int drow = w * 16 + j * 8 + (lane >> 3);
      gload16(VtB + drow * 1024 + t * 64 + (lane & 7) * 8, &Vts[w * 1024 + j * 512]);
    }
    // ---- stage (mask + klm) * temp2 as bf16, transposed [s][l] ----
    {
      int lrow = tid >> 2, sc0 = (tid & 3) * 16;
      const float* mrow = mask + (lblk * 64 + lrow) * 1024 + t * 64 + sc0;
      const float* krow = klm + n * 1024 + t * 64 + sc0;
#pragma unroll
      for (int j = 0; j < 4; ++j) {
        float4 mv = *(const float4*)(mrow + j * 4);
        float4 kv = *(const float4*)(krow + j * 4);
        Mz[(sc0 + j*4 + 0) * 66 + lrow] = f2bf((mv.x + kv.x) * temp2);
        Mz[(sc0 + j*4 + 1) * 66 + lrow] = f2bf((mv.y + kv.y) * temp2);
        Mz[(sc0 + j*4 + 2) * 66 + lrow] = f2bf((mv.z + kv.z) * temp2);
        Mz[(sc0 + j*4 + 3) * 66 + lrow] = f2bf((mv.w + kv.w) * temp2);
      }
    }
    __syncthreads();

    unsigned int pw0 = pospk[posbase + t * 2];
    unsigned int pw1 = pospk[posbase + t * 2 + 1];

    // ---- scores: S^T[s][q] via mfma(K, Q); bias in log2 domain ----
    f32x4 sv[4];
#pragma unroll
    for (int ss = 0; ss < 4; ++ss) {
      f32x4 acc = {0, 0, 0, 0};
      const int row = (ss * 16 + c) * 64;
      bf16x8 kf0 = __builtin_bit_cast(bf16x8, *(const u32x4*)&Kt[row + ((g       ^ (c & 7)) * 8)]);
      bf16x8 kf1 = __builtin_bit_cast(bf16x8, *(const u32x4*)&Kt[row + (((4 + g) ^ (c & 7)) * 8)]);
      acc = __builtin_amdgcn_mfma_f32_16x16x32_bf16(kf0, qf[0], acc, 0, 0, 0);
      acc = __builtin_amdgcn_mfma_f32_16x16x32_bf16(kf1, qf[1], acc, 0, 0, 0);
      unsigned int pw = (ss & 2) ? pw1 : pw0;
#pragma unroll
      for (int r = 0; r < 4; ++r) {
        int s_ = ss * 16 + g * 4 + r;                // tile-local s of this reg
        float mz = bf2f(Mz[s_ * 66 + (w * 16 + c)]);
        float bit = (float)((pw >> (s_ & 31)) & 1u);
        sv[ss][r] = fmaf(acc[r], temp2, mz) + bit * delta2;
      }
    }
    // ---- online softmax (row q = c lives in lanes {c, c+16, c+32, c+48}) ----
    float tmax = -1e30f;
#pragma unroll
    for (int ss = 0; ss < 4; ++ss)
#pragma unroll
      for (int r = 0; r < 4; ++r) tmax = fmaxf(tmax, sv[ss][r]);
    tmax = fmaxf(tmax, __shfl_xor(tmax, 16));
    tmax = fmaxf(tmax, __shfl_xor(tmax, 32));
    float mnew = fmaxf(mrun, tmax);
    float scale = __builtin_amdgcn_exp2f(mrun - mnew);
    float tsum = 0.f;
#pragma unroll
    for (int ss = 0; ss < 4; ++ss)
#pragma unroll
      for (int r = 0; r < 4; ++r) {
        float p = __builtin_amdgcn_exp2f(sv[ss][r] - mnew);
        sv[ss][r] = p;
        tsum += p;
      }
    tsum += __shfl_xor(tsum, 16);
    tsum += __shfl_xor(tsum, 32);
    lrun = lrun * scale + tsum;
    mrun = mnew;
#pragma unroll
    for (int ds = 0; ds < 4; ++ds) Oc[ds] = Oc[ds] * scale;

    // ---- P^T -> per-wave swizzled LDS (pairs of adjacent s packed) ----
#pragma unroll
    for (int ss = 0; ss < 4; ++ss)
#pragma unroll
      for (int pr = 0; pr < 2; ++pr) {
        unsigned int val = (unsigned)f2bf(sv[ss][pr * 2]) |
                           ((unsigned)f2bf(sv[ss][pr * 2 + 1]) << 16);
        int sp = ss * 8 + g * 2 + pr;                // s>>1
        Pb[w][c * 32 + (((sp >> 2) ^ (c & 7)) << 2) + (sp & 3)] = val;
      }
    // ---- PV: O^T[d][q] += V^T x P^T  (A = V^T frag, B = P^T frag) ----
#pragma unroll
    for (int w2 = 0; w2 < 2; ++w2) {
      bf16x8 pf = __builtin_bit_cast(bf16x8,
          *(const u32x4*)&Pb[w][c * 32 + (((w2 * 4 + g) ^ (c & 7)) << 2)]);
#pragma unroll
      for (int ds = 0; ds < 4; ++ds) {
        bf16x8 vf = __builtin_bit_cast(bf16x8,
            *(const u32x4*)&Vts[(ds * 16 + c) * 64 + (((w2 * 4 + g) ^ (c & 7)) * 8)]);
        Oc[ds] = __builtin_amdgcn_mfma_f32_16x16x32_bf16(vf, pf, Oc[ds], 0, 0, 0);
      }
    }
  }
  // ---- epilogue: divide by l, store O (lane holds d = ds*16+4g+r, q = c) ----
  float inv = 1.0f / lrun;
  float* orow = out + ((n * 1024 + l) * 16 + h) * 64;
#pragma unroll
  for (int ds = 0; ds < 4; ++ds) {
    float4 o;
    o.x = Oc[ds][0] * inv; o.y = Oc[ds][1] * inv;
    o.z = Oc[ds][2] * inv; o.w = Oc[ds][3] * inv;
    *(float4*)(orow + ds * 16 + g * 4) = o;
  }
}

extern "C" void kernel_launch(void* const* d_in, const int* in_sizes, int n_in,
                              void* d_out, int out_size, void* d_ws, size_t ws_size,
                              hipStream_t stream) {
  const float* Q    = (const float*)d_in[0];
  const float* K    = (const float*)d_in[1];
  const float* V    = (const float*)d_in[2];
  const float* mask = (const float*)d_in[3];
  const float* klm  = (const float*)d_in[4];
  const float* ptab = (const float*)d_in[5];
  const int*   pos  = (const int*)d_in[6];
  float* out = (float*)d_out;

  char* ws = (char*)d_ws;
  unsigned int*   pospk = (unsigned int*)ws;                          // 512 KB
  unsigned short* Kp    = (unsigned short*)(ws + (1 << 19));          // 8 MB
  unsigned short* Vt    = (unsigned short*)(ws + (1 << 19) + (8 << 20)); // 8 MB

  k_pack_pos<<<16384, 256, 0, stream>>>(pos, pospk);
  k_prep_k<<<256, 256, 0, stream>>>(K, Kp);
  k_prep_v<<<1024, 256, 0, stream>>>(V, Vt);
  k_attn<<<1024, 256, 0, stream>>>(Q, mask, klm, ptab, pospk, Kp, Vt, out);
}

// Round 2
// 84.876 us; speedup vs baseline: 1.0742x; 1.0742x over previous
//
#include <hip/hip_runtime.h>

// FullAttention_Spatial: N=4, L=S=1024, H=16, E=D=64, NUM_POS=2, fp32 in/out.
//
// score = temp*(QK + attn_mask[l,s] + klm[n,s]) + pos_table[pos[n,l,s]][h]
// pos in {0,1} => bias = T0[h] + bit*(T1[h]-T0[h]); T0 cancels in softmax.
// All softmax math in log2 domain. Q is pre-scaled by temp2 = temp*log2e
// before bf16 pack, so score2 = (Qs)K + CM[n,l,s] + bit*delta2.
//
// Prepass 1: pack pos bits (ballot)            -> ws[0.5 MB]
// Prepass 2: K fp32 [n][s][h][e] -> bf16 [n][h][s][e], 16B blocks ^= (s&7)
// Prepass 3: V fp32 [n][s][h][d] -> bf16 [n][h][d][s], per-64s-seg blocks ^= (d&7)
// Prepass 4 (if ws allows): CM[n][l][s] = (mask[l][s]+klm[n][s])*temp2, bf16
// Main: flash attention, mfma_f32_16x16x32_bf16, swapped QK^T (S^T layout),
//       K/V tiles staged with global_load_lds (16B), O^T accumulated, /l at end.
//       Bias read straight to registers (no LDS mask tile). Defer-max (THR=4).

typedef __attribute__((ext_vector_type(8))) __bf16 bf16x8;
typedef __attribute__((ext_vector_type(4))) float f32x4;
typedef __attribute__((ext_vector_type(4))) unsigned int u32x4;

#define TEMP2 (0.125f * 1.4426950408889634f)

static __device__ __forceinline__ unsigned short f2bf(float x) {
  unsigned int u = __builtin_bit_cast(unsigned int, x);
  u += 0x7FFFu + ((u >> 16) & 1u);
  return (unsigned short)(u >> 16);
}
static __device__ __forceinline__ unsigned int cvtpk(float lo, float hi) {
  unsigned int r;
  asm("v_cvt_pk_bf16_f32 %0, %1, %2" : "=v"(r) : "v"(lo), "v"(hi));
  return r;
}
static __device__ __forceinline__ void gload16(const void* g, void* l) {
  __builtin_amdgcn_global_load_lds((const __attribute__((address_space(1))) void*)g,
                                   (__attribute__((address_space(3))) void*)l, 16, 0, 0);
}

// ---------------- prepass 1: pack pos bits ----------------
__global__ __launch_bounds__(256) void k_pack_pos(const int* __restrict__ pos,
                                                  unsigned int* __restrict__ out) {
  int gi = blockIdx.x * 256 + threadIdx.x;
  int v = pos[gi];
  unsigned long long m = __ballot(v & 1);
  int lane = threadIdx.x & 63;
  if (lane == 0) out[gi >> 5] = (unsigned int)m;
  else if (lane == 32) out[gi >> 5] = (unsigned int)(m >> 32);
}

// ---------------- prepass 2: K relayout ----------------
__global__ __launch_bounds__(256) void k_prep_k(const float* __restrict__ K,
                                                unsigned short* __restrict__ Kp) {
  int idx = blockIdx.x * 256 + threadIdx.x;   // ((n*1024+s)*16+h)
  int n = idx >> 14, s = (idx >> 4) & 1023, h = idx & 15;
  const float* src = K + idx * 64;
  unsigned short row[64];
#pragma unroll
  for (int j = 0; j < 16; ++j) {
    float4 v = *(const float4*)(src + j * 4);
    row[j*4+0] = f2bf(v.x); row[j*4+1] = f2bf(v.y);
    row[j*4+2] = f2bf(v.z); row[j*4+3] = f2bf(v.w);
  }
  unsigned short* dst = Kp + ((n * 16 + h) * 1024 + s) * 64;
#pragma unroll
  for (int b = 0; b < 8; ++b) {
    int pb = b ^ (s & 7);
    *(u32x4*)(dst + pb * 8) = *(const u32x4*)(&row[b * 8]);
  }
}

// ---------------- prepass 3: V transpose ----------------
__global__ __launch_bounds__(256) void k_prep_v(const float* __restrict__ V,
                                                unsigned short* __restrict__ Vt) {
  __shared__ float ld[64][65];
  int bid = blockIdx.x;
  int t = bid & 15, h = (bid >> 4) & 15, n = bid >> 8;
  int tid = threadIdx.x;
  {
    int s = tid >> 2, dq = (tid & 3) * 16;
    const float* src = V + ((n * 1024 + t * 64 + s) * 16 + h) * 64 + dq;
#pragma unroll
    for (int j = 0; j < 4; ++j) {
      float4 v = *(const float4*)(src + j * 4);
      ld[s][dq + j*4 + 0] = v.x; ld[s][dq + j*4 + 1] = v.y;
      ld[s][dq + j*4 + 2] = v.z; ld[s][dq + j*4 + 3] = v.w;
    }
  }
  __syncthreads();
  {
    int d = tid >> 2, sq = (tid & 3) * 16;
    unsigned short vals[16];
#pragma unroll
    for (int k = 0; k < 16; ++k) vals[k] = f2bf(ld[sq + k][d]);
    unsigned short* dst = Vt + ((n * 16 + h) * 64 + d) * 1024 + t * 64;
#pragma unroll
    for (int cb = 0; cb < 2; ++cb) {
      int blk = (sq >> 3) + cb;
      int pb = blk ^ (d & 7);
      *(u32x4*)(dst + pb * 8) = *(const u32x4*)(&vals[cb * 8]);
    }
  }
}

// ---------------- prepass 4: combined mask (bf16, pre-scaled) ----------------
__global__ __launch_bounds__(256) void k_prep_cm(const float* __restrict__ mask,
                                                 const float* __restrict__ klm,
                                                 unsigned short* __restrict__ CM) {
  int idx = blockIdx.x * 256 + threadIdx.x;   // 262144 threads, 16 elems each
  int flat = idx * 16;
  int n = flat >> 20, l = (flat >> 10) & 1023, s0 = flat & 1023;
  const float* mrow = mask + l * 1024 + s0;
  const float* krow = klm + n * 1024 + s0;
  unsigned int o[8];
#pragma unroll
  for (int j = 0; j < 4; ++j) {
    float4 mv = *(const float4*)(mrow + j * 4);
    float4 kv = *(const float4*)(krow + j * 4);
    o[j*2+0] = cvtpk((mv.x + kv.x) * TEMP2, (mv.y + kv.y) * TEMP2);
    o[j*2+1] = cvtpk((mv.z + kv.z) * TEMP2, (mv.w + kv.w) * TEMP2);
  }
  *(u32x4*)(CM + flat)     = *(const u32x4*)(&o[0]);
  *(u32x4*)(CM + flat + 8) = *(const u32x4*)(&o[4]);
}

// ---------------- main flash-attention kernel ----------------
// grid 1024 = (lblk<<6) | (h<<2) | n ; 4 waves x 16 q-rows.
template <bool USE_CM>
__global__ __launch_bounds__(256, 4) void k_attn(
    const float* __restrict__ Q, const float* __restrict__ mask,
    const float* __restrict__ klm, const float* __restrict__ ptab,
    const unsigned int* __restrict__ pospk,
    const unsigned short* __restrict__ Kp, const unsigned short* __restrict__ Vt,
    const unsigned short* __restrict__ CMp,
    float* __restrict__ out) {
  __shared__ __align__(16) unsigned short Kt[4096];    // [64 s][64 e] swizzled
  __shared__ __align__(16) unsigned short Vts[4096];   // [64 d][64 s] swizzled
  __shared__ __align__(16) unsigned int Pb[4][512];    // per-wave P^T, swizzled

  int bid = blockIdx.x;
  int n = bid & 3, h = (bid >> 2) & 15, lblk = bid >> 6;
  int tid = threadIdx.x;
  int w = tid >> 6, lane = tid & 63;
  int g = lane >> 4, c = lane & 15;
  int l = lblk * 64 + w * 16 + c;      // this lane's q-row (global)

  // Q fragments, PRE-SCALED by temp2 (B-operand of swapped QK^T)
  const float* qrow = Q + ((n * 1024 + l) * 16 + h) * 64;
  bf16x8 qf[2];
#pragma unroll
  for (int e = 0; e < 2; ++e) {
    float4 a = *(const float4*)(qrow + e * 32 + g * 8);
    float4 b = *(const float4*)(qrow + e * 32 + g * 8 + 4);
    u32x4 pk;
    pk[0] = cvtpk(a.x * TEMP2, a.y * TEMP2);
    pk[1] = cvtpk(a.z * TEMP2, a.w * TEMP2);
    pk[2] = cvtpk(b.x * TEMP2, b.y * TEMP2);
    pk[3] = cvtpk(b.z * TEMP2, b.w * TEMP2);
    qf[e] = __builtin_bit_cast(bf16x8, pk);
  }
  const float delta2 = (ptab[16 + h] - ptab[h]) * 1.4426950408889634f;

  float mrun = -1e30f, lrun = 0.f;
  f32x4 Oc[4] = {{0,0,0,0},{0,0,0,0},{0,0,0,0},{0,0,0,0}};

  const unsigned short* KpB = Kp + (n * 16 + h) * (1024 * 64);
  const unsigned short* VtB = Vt + (n * 16 + h) * (64 * 1024);
  const unsigned short* CMb = USE_CM ? (CMp + (n * 1024 + l) * 1024) : nullptr;
  const float* mrowB = mask + l * 1024;
  const float* krowB = klm + n * 1024;
  const int posbase = (n * 1024 + l) * 32;

  for (int t = 0; t < 16; ++t) {
    __syncthreads();
    // ---- stage K & V tiles: global_load_lds, 16B/lane, 2 calls/wave each ----
#pragma unroll
    for (int j = 0; j < 2; ++j) {
      gload16(KpB + t * 4096 + w * 1024 + j * 512 + lane * 8, &Kt[w * 1024 + j * 512]);
      int drow = w * 16 + j * 8 + (lane >> 3);
      gload16(VtB + drow * 1024 + t * 64 + (lane & 7) * 8, &Vts[w * 1024 + j * 512]);
    }
    __syncthreads();

    unsigned int pw0 = pospk[posbase + t * 2];
    unsigned int pw1 = pospk[posbase + t * 2 + 1];

    // ---- scores: S^T[s][q] via mfma(K, Qs); bias direct to registers ----
    f32x4 sv[4];
#pragma unroll
    for (int ss = 0; ss < 4; ++ss) {
      f32x4 acc = {0, 0, 0, 0};
      const int row = (ss * 16 + c) * 64;
      bf16x8 kf0 = __builtin_bit_cast(bf16x8, *(const u32x4*)&Kt[row + ((g       ^ (c & 7)) * 8)]);
      bf16x8 kf1 = __builtin_bit_cast(bf16x8, *(const u32x4*)&Kt[row + (((4 + g) ^ (c & 7)) * 8)]);
      __builtin_amdgcn_s_setprio(1);
      acc = __builtin_amdgcn_mfma_f32_16x16x32_bf16(kf0, qf[0], acc, 0, 0, 0);
      acc = __builtin_amdgcn_mfma_f32_16x16x32_bf16(kf1, qf[1], acc, 0, 0, 0);
      __builtin_amdgcn_s_setprio(0);

      float bias[4];
      if constexpr (USE_CM) {
        uint2 cmv = *(const uint2*)(CMb + t * 64 + ss * 16 + g * 4);
        bias[0] = __builtin_bit_cast(float, cmv.x << 16);
        bias[1] = __builtin_bit_cast(float, cmv.x & 0xFFFF0000u);
        bias[2] = __builtin_bit_cast(float, cmv.y << 16);
        bias[3] = __builtin_bit_cast(float, cmv.y & 0xFFFF0000u);
      } else {
        float4 mv = *(const float4*)(mrowB + t * 64 + ss * 16 + g * 4);
        float4 kv = *(const float4*)(krowB + t * 64 + ss * 16 + g * 4);
        bias[0] = (mv.x + kv.x) * TEMP2; bias[1] = (mv.y + kv.y) * TEMP2;
        bias[2] = (mv.z + kv.z) * TEMP2; bias[3] = (mv.w + kv.w) * TEMP2;
      }
      unsigned int pw = (ss & 2) ? pw1 : pw0;
#pragma unroll
      for (int r = 0; r < 4; ++r) {
        int s_ = ss * 16 + g * 4 + r;                // tile-local s of this reg
        float bitf = (float)((pw >> (s_ & 31)) & 1u);
        sv[ss][r] = fmaf(bitf, delta2, acc[r] + bias[r]);
      }
    }
    // ---- online softmax (row q = c lives in lanes {c, c+16, c+32, c+48}) ----
    float tmax = fmaxf(fmaxf(sv[0][0], sv[0][1]), fmaxf(sv[0][2], sv[0][3]));
#pragma unroll
    for (int ss = 1; ss < 4; ++ss)
#pragma unroll
      for (int r = 0; r < 4; ++r) tmax = fmaxf(tmax, sv[ss][r]);
    tmax = fmaxf(tmax, __shfl_xor(tmax, 16));
    tmax = fmaxf(tmax, __shfl_xor(tmax, 32));
    // defer-max (T13): only rescale when the running reference grows by >4
    if (!__all(tmax <= mrun + 4.0f)) {
      float mnew = fmaxf(mrun, tmax);
      float sc = __builtin_amdgcn_exp2f(mrun - mnew);
      lrun *= sc;
#pragma unroll
      for (int ds = 0; ds < 4; ++ds) Oc[ds] = Oc[ds] * sc;
      mrun = mnew;
    }
    float tsum = 0.f;
#pragma unroll
    for (int ss = 0; ss < 4; ++ss)
#pragma unroll
      for (int r = 0; r < 4; ++r) {
        float p = __builtin_amdgcn_exp2f(sv[ss][r] - mrun);
        sv[ss][r] = p;
        tsum += p;
      }
    tsum += __shfl_xor(tsum, 16);
    tsum += __shfl_xor(tsum, 32);
    lrun += tsum;

    // ---- P^T -> per-wave swizzled LDS (pairs of adjacent s packed) ----
#pragma unroll
    for (int ss = 0; ss < 4; ++ss)
#pragma unroll
      for (int pr = 0; pr < 2; ++pr) {
        unsigned int val = cvtpk(sv[ss][pr * 2], sv[ss][pr * 2 + 1]);
        int sp = ss * 8 + g * 2 + pr;                // s>>1
        Pb[w][c * 32 + (((sp >> 2) ^ (c & 7)) << 2) + (sp & 3)] = val;
      }
    // ---- PV: O^T[d][q] += V^T x P^T  (A = V^T frag, B = P^T frag) ----
    __builtin_amdgcn_s_setprio(1);
#pragma unroll
    for (int w2 = 0; w2 < 2; ++w2) {
      bf16x8 pf = __builtin_bit_cast(bf16x8,
          *(const u32x4*)&Pb[w][c * 32 + (((w2 * 4 + g) ^ (c & 7)) << 2)]);
#pragma unroll
      for (int ds = 0; ds < 4; ++ds) {
        bf16x8 vf = __builtin_bit_cast(bf16x8,
            *(const u32x4*)&Vts[(ds * 16 + c) * 64 + (((w2 * 4 + g) ^ (c & 7)) * 8)]);
        Oc[ds] = __builtin_amdgcn_mfma_f32_16x16x32_bf16(vf, pf, Oc[ds], 0, 0, 0);
      }
    }
    __builtin_amdgcn_s_setprio(0);
  }
  // ---- epilogue: divide by l, store O (lane holds d = ds*16+4g+r, q = c) ----
  float inv = 1.0f / lrun;
  float* orow = out + ((n * 1024 + l) * 16 + h) * 64;
#pragma unroll
  for (int ds = 0; ds < 4; ++ds) {
    float4 o;
    o.x = Oc[ds][0] * inv; o.y = Oc[ds][1] * inv;
    o.z = Oc[ds][2] * inv; o.w = Oc[ds][3] * inv;
    *(float4*)(orow + ds * 16 + g * 4) = o;
  }
}

extern "C" void kernel_launch(void* const* d_in, const int* in_sizes, int n_in,
                              void* d_out, int out_size, void* d_ws, size_t ws_size,
                              hipStream_t stream) {
  const float* Q    = (const float*)d_in[0];
  const float* K    = (const float*)d_in[1];
  const float* V    = (const float*)d_in[2];
  const float* mask = (const float*)d_in[3];
  const float* klm  = (const float*)d_in[4];
  const float* ptab = (const float*)d_in[5];
  const int*   pos  = (const int*)d_in[6];
  float* out = (float*)d_out;

  char* ws = (char*)d_ws;
  unsigned int*   pospk = (unsigned int*)ws;                               // 512 KB
  unsigned short* Kp    = (unsigned short*)(ws + (1 << 19));               // 8 MB
  unsigned short* Vt    = (unsigned short*)(ws + (1 << 19) + (8 << 20));   // 8 MB
  unsigned short* CM    = (unsigned short*)(ws + (1 << 19) + (16 << 20));  // 8 MB
  const size_t need_cm = (size_t)(1 << 19) + (size_t)(24 << 20);
  const bool use_cm = ws_size >= need_cm;

  k_pack_pos<<<16384, 256, 0, stream>>>(pos, pospk);
  k_prep_k<<<256, 256, 0, stream>>>(K, Kp);
  k_prep_v<<<1024, 256, 0, stream>>>(V, Vt);
  if (use_cm) {
    k_prep_cm<<<1024, 256, 0, stream>>>(mask, klm, CM);
    k_attn<true><<<1024, 256, 0, stream>>>(Q, mask, klm, ptab, pospk, Kp, Vt, CM, out);
  } else {
    k_attn<false><<<1024, 256, 0, stream>>>(Q, mask, klm, ptab, pospk, Kp, Vt, nullptr, out);
  }
}

// Round 3
// 80.006 us; speedup vs baseline: 1.1396x; 1.0609x over previous
//
#include <hip/hip_runtime.h>

// FullAttention_Spatial: N=4, L=S=1024, H=16, E=D=64, NUM_POS=2, fp32 in/out.
//
// score = temp*(QK + attn_mask[l,s] + klm[n,s]) + pos_table[pos[n,l,s]][h]
// pos in {0,1} => bias = T0[h] + bit*(T1[h]-T0[h]); T0 cancels in softmax.
// All softmax math in log2 domain. Q pre-scaled by temp2 = temp*log2e.
//
// k_prep (fused, role-split by blockIdx):
//   [0,256)      K fp32 [n][s][h][e] -> bf16 [n][h][s][e], 16B blocks ^= (s&7)
//   [256,1280)   V fp32 [n][s][h][d] -> bf16 [n][h][d][s], 16B blocks ^= (d&7)
//   [1280,2304)  CM[n][l][s] = (mask[l][s]+klm[n][s])*temp2, bf16
//   [2304,18688) pack pos bits (ballot) -> pospk
// k_attn: flash attention, mfma_f32_16x16x32_bf16, swapped QK^T (S^T layout),
//   2-phase double-buffered K/V staging (global_load_lds 16B), ONE barrier/tile,
//   pos-bits + CM bias prefetched 1 tile ahead (register-only compute phase),
//   O^T accumulated fp32, /l at end. Defer-max (THR=4).

typedef __attribute__((ext_vector_type(8))) __bf16 bf16x8;
typedef __attribute__((ext_vector_type(4))) float f32x4;
typedef __attribute__((ext_vector_type(4))) unsigned int u32x4;

#define TEMP2 (0.125f * 1.4426950408889634f)

static __device__ __forceinline__ unsigned short f2bf(float x) {
  unsigned int u = __builtin_bit_cast(unsigned int, x);
  u += 0x7FFFu + ((u >> 16) & 1u);
  return (unsigned short)(u >> 16);
}
static __device__ __forceinline__ unsigned int cvtpk(float lo, float hi) {
  unsigned int r;
  asm("v_cvt_pk_bf16_f32 %0, %1, %2" : "=v"(r) : "v"(lo), "v"(hi));
  return r;
}
static __device__ __forceinline__ void gload16(const void* g, void* l) {
  __builtin_amdgcn_global_load_lds((const __attribute__((address_space(1))) void*)g,
                                   (__attribute__((address_space(3))) void*)l, 16, 0, 0);
}

// ---------------- fused prepass ----------------
__global__ __launch_bounds__(256) void k_prep(
    const int* __restrict__ pos, unsigned int* __restrict__ pospk,
    const float* __restrict__ K, unsigned short* __restrict__ Kp,
    const float* __restrict__ V, unsigned short* __restrict__ Vt,
    const float* __restrict__ mask, const float* __restrict__ klm,
    unsigned short* __restrict__ CM, int use_cm) {
  __shared__ float ld[64][65];
  int b = blockIdx.x;
  int tid = threadIdx.x;
  if (b < 256) {
    // ---- K relayout: thread = (n, s, h) ----
    int idx = b * 256 + tid;
    int s = (idx >> 4) & 1023;
    const float* src = K + idx * 64;
    unsigned short row[64];
#pragma unroll
    for (int j = 0; j < 16; ++j) {
      float4 v = *(const float4*)(src + j * 4);
      row[j*4+0] = f2bf(v.x); row[j*4+1] = f2bf(v.y);
      row[j*4+2] = f2bf(v.z); row[j*4+3] = f2bf(v.w);
    }
    int n = idx >> 14, h = idx & 15;
    unsigned short* dst = Kp + ((n * 16 + h) * 1024 + s) * 64;
#pragma unroll
    for (int bb = 0; bb < 8; ++bb) {
      int pb = bb ^ (s & 7);
      *(u32x4*)(dst + pb * 8) = *(const u32x4*)(&row[bb * 8]);
    }
  } else if (b < 1280) {
    // ---- V transpose: block = (n, h, t), 64s x 64d tile ----
    int vb = b - 256;
    int t = vb & 15, h = (vb >> 4) & 15, n = vb >> 8;
    {
      int s = tid >> 2, dq = (tid & 3) * 16;
      const float* src = V + ((n * 1024 + t * 64 + s) * 16 + h) * 64 + dq;
#pragma unroll
      for (int j = 0; j < 4; ++j) {
        float4 v = *(const float4*)(src + j * 4);
        ld[s][dq + j*4 + 0] = v.x; ld[s][dq + j*4 + 1] = v.y;
        ld[s][dq + j*4 + 2] = v.z; ld[s][dq + j*4 + 3] = v.w;
      }
    }
    __syncthreads();
    {
      int d = tid >> 2, sq = (tid & 3) * 16;
      unsigned short vals[16];
#pragma unroll
      for (int k = 0; k < 16; ++k) vals[k] = f2bf(ld[sq + k][d]);
      unsigned short* dst = Vt + ((n * 16 + h) * 64 + d) * 1024 + t * 64;
#pragma unroll
      for (int cb = 0; cb < 2; ++cb) {
        int blk = (sq >> 3) + cb;
        int pb = blk ^ (d & 7);
        *(u32x4*)(dst + pb * 8) = *(const u32x4*)(&vals[cb * 8]);
      }
    }
  } else if (b < 2304) {
    // ---- combined mask (bf16, pre-scaled) ----
    if (!use_cm) return;
    int flat = (b - 1280) * 256 * 16 + tid * 16;
    int n = flat >> 20, l = (flat >> 10) & 1023, s0 = flat & 1023;
    const float* mrow = mask + l * 1024 + s0;
    const float* krow = klm + n * 1024 + s0;
    unsigned int o[8];
#pragma unroll
    for (int j = 0; j < 4; ++j) {
      float4 mv = *(const float4*)(mrow + j * 4);
      float4 kv = *(const float4*)(krow + j * 4);
      o[j*2+0] = cvtpk((mv.x + kv.x) * TEMP2, (mv.y + kv.y) * TEMP2);
      o[j*2+1] = cvtpk((mv.z + kv.z) * TEMP2, (mv.w + kv.w) * TEMP2);
    }
    *(u32x4*)(CM + flat)     = *(const u32x4*)(&o[0]);
    *(u32x4*)(CM + flat + 8) = *(const u32x4*)(&o[4]);
  } else {
    // ---- pack pos bits ----
    int gi = (b - 2304) * 256 + tid;
    int v = pos[gi];
    unsigned long long m = __ballot(v & 1);
    int lane = tid & 63;
    if (lane == 0) pospk[gi >> 5] = (unsigned int)m;
    else if (lane == 32) pospk[gi >> 5] = (unsigned int)(m >> 32);
  }
}

// ---------------- main flash-attention kernel ----------------
// grid 1024 = (lblk<<6) | (h<<2) | n ; 4 waves x 16 q-rows; 2-phase dbuf.
template <bool USE_CM>
__global__ __launch_bounds__(256, 4) void k_attn(
    const float* __restrict__ Q, const float* __restrict__ mask,
    const float* __restrict__ klm, const float* __restrict__ ptab,
    const unsigned int* __restrict__ pospk,
    const unsigned short* __restrict__ Kp, const unsigned short* __restrict__ Vt,
    const unsigned short* __restrict__ CMp,
    float* __restrict__ out) {
  __shared__ __align__(16) unsigned short Kt[2][4096];   // [64 s][64 e] swizzled
  __shared__ __align__(16) unsigned short Vts[2][4096];  // [64 d][64 s] swizzled
  __shared__ __align__(16) unsigned int Pb[4][512];      // per-wave P^T, swizzled

  int bid = blockIdx.x;
  int n = bid & 3, h = (bid >> 2) & 15, lblk = bid >> 6;
  int tid = threadIdx.x;
  int w = tid >> 6, lane = tid & 63;
  int g = lane >> 4, c = lane & 15;
  int l = lblk * 64 + w * 16 + c;      // this lane's q-row (global)

  // Q fragments, PRE-SCALED by temp2 (B-operand of swapped QK^T)
  const float* qrow = Q + ((n * 1024 + l) * 16 + h) * 64;
  bf16x8 qf[2];
#pragma unroll
  for (int e = 0; e < 2; ++e) {
    float4 a = *(const float4*)(qrow + e * 32 + g * 8);
    float4 bq = *(const float4*)(qrow + e * 32 + g * 8 + 4);
    u32x4 pk;
    pk[0] = cvtpk(a.x * TEMP2, a.y * TEMP2);
    pk[1] = cvtpk(a.z * TEMP2, a.w * TEMP2);
    pk[2] = cvtpk(bq.x * TEMP2, bq.y * TEMP2);
    pk[3] = cvtpk(bq.z * TEMP2, bq.w * TEMP2);
    qf[e] = __builtin_bit_cast(bf16x8, pk);
  }
  const float delta2 = (ptab[16 + h] - ptab[h]) * 1.4426950408889634f;

  float mrun = -1e30f, lrun = 0.f;
  f32x4 Oc[4] = {{0,0,0,0},{0,0,0,0},{0,0,0,0},{0,0,0,0}};

  const unsigned short* KpB = Kp + (n * 16 + h) * (1024 * 64);
  const unsigned short* VtB = Vt + (n * 16 + h) * (64 * 1024);
  const unsigned short* CMb = USE_CM ? (CMp + (n * 1024 + l) * 1024) : nullptr;
  const float* mrowB = mask + l * 1024;
  const float* krowB = klm + n * 1024;
  const int posbase = (n * 1024 + l) * 32;

  // ---- prologue: stage tile 0 into buf 0, prefetch bias/pos for tile 0 ----
  unsigned int pw0 = pospk[posbase];
  unsigned int pw1 = pospk[posbase + 1];
  uint2 cm[4];
  if constexpr (USE_CM) {
#pragma unroll
    for (int ss = 0; ss < 4; ++ss)
      cm[ss] = *(const uint2*)(CMb + ss * 16 + g * 4);
  }
#pragma unroll
  for (int j = 0; j < 2; ++j) {
    gload16(KpB + w * 1024 + j * 512 + lane * 8, &Kt[0][w * 1024 + j * 512]);
    int drow = w * 16 + j * 8 + (lane >> 3);
    gload16(VtB + drow * 1024 + (lane & 7) * 8, &Vts[0][w * 1024 + j * 512]);
  }
  __syncthreads();

#define BODY(BUF, T, STG)                                                      \
  {                                                                            \
    unsigned int npw0 = 0, npw1 = 0;                                           \
    uint2 ncm[4];                                                              \
    if (STG) {                                                                 \
      _Pragma("unroll")                                                        \
      for (int j = 0; j < 2; ++j) {                                            \
        gload16(KpB + (T + 1) * 4096 + w * 1024 + j * 512 + lane * 8,          \
                &Kt[BUF ^ 1][w * 1024 + j * 512]);                             \
        int drow = w * 16 + j * 8 + (lane >> 3);                               \
        gload16(VtB + drow * 1024 + (T + 1) * 64 + (lane & 7) * 8,             \
                &Vts[BUF ^ 1][w * 1024 + j * 512]);                            \
      }                                                                        \
      npw0 = pospk[posbase + (T + 1) * 2];                                     \
      npw1 = pospk[posbase + (T + 1) * 2 + 1];                                 \
      if constexpr (USE_CM) {                                                  \
        _Pragma("unroll")                                                      \
        for (int ss = 0; ss < 4; ++ss)                                         \
          ncm[ss] = *(const uint2*)(CMb + (T + 1) * 64 + ss * 16 + g * 4);     \
      }                                                                        \
    }                                                                          \
    /* ---- scores: S^T[s][q] via mfma(K, Qs) ---- */                          \
    f32x4 sv[4];                                                               \
    _Pragma("unroll")                                                          \
    for (int ss = 0; ss < 4; ++ss) {                                           \
      f32x4 acc = {0, 0, 0, 0};                                                \
      const int row = (ss * 16 + c) * 64;                                      \
      bf16x8 kf0 = __builtin_bit_cast(bf16x8,                                  \
          *(const u32x4*)&Kt[BUF][row + ((g ^ (c & 7)) * 8)]);                 \
      bf16x8 kf1 = __builtin_bit_cast(bf16x8,                                  \
          *(const u32x4*)&Kt[BUF][row + (((4 + g) ^ (c & 7)) * 8)]);           \
      __builtin_amdgcn_s_setprio(1);                                           \
      acc = __builtin_amdgcn_mfma_f32_16x16x32_bf16(kf0, qf[0], acc, 0, 0, 0); \
      acc = __builtin_amdgcn_mfma_f32_16x16x32_bf16(kf1, qf[1], acc, 0, 0, 0); \
      __builtin_amdgcn_s_setprio(0);                                           \
      float bias[4];                                                           \
      if constexpr (USE_CM) {                                                  \
        bias[0] = __builtin_bit_cast(float, cm[ss].x << 16);                   \
        bias[1] = __builtin_bit_cast(float, cm[ss].x & 0xFFFF0000u);           \
        bias[2] = __builtin_bit_cast(float, cm[ss].y << 16);                   \
        bias[3] = __builtin_bit_cast(float, cm[ss].y & 0xFFFF0000u);           \
      } else {                                                                 \
        float4 mv = *(const float4*)(mrowB + (T) * 64 + ss * 16 + g * 4);      \
        float4 kv = *(const float4*)(krowB + (T) * 64 + ss * 16 + g * 4);      \
        bias[0] = (mv.x + kv.x) * TEMP2; bias[1] = (mv.y + kv.y) * TEMP2;      \
        bias[2] = (mv.z + kv.z) * TEMP2; bias[3] = (mv.w + kv.w) * TEMP2;      \
      }                                                                        \
      unsigned int pw = (ss & 2) ? pw1 : pw0;                                  \
      _Pragma("unroll")                                                        \
      for (int r = 0; r < 4; ++r) {                                            \
        int s_ = ss * 16 + g * 4 + r;                                          \
        float bitf = (float)((pw >> (s_ & 31)) & 1u);                          \
        sv[ss][r] = fmaf(bitf, delta2, acc[r] + bias[r]);                      \
      }                                                                        \
    }                                                                          \
    /* ---- online softmax ---- */                                             \
    float tmax = fmaxf(fmaxf(sv[0][0], sv[0][1]), fmaxf(sv[0][2], sv[0][3]));  \
    _Pragma("unroll")                                                          \
    for (int ss = 1; ss < 4; ++ss)                                             \
      { tmax = fmaxf(tmax, fmaxf(fmaxf(sv[ss][0], sv[ss][1]),                  \
                                 fmaxf(sv[ss][2], sv[ss][3]))); }              \
    tmax = fmaxf(tmax, __shfl_xor(tmax, 16));                                  \
    tmax = fmaxf(tmax, __shfl_xor(tmax, 32));                                  \
    if (!__all(tmax <= mrun + 4.0f)) {                                         \
      float mnew = fmaxf(mrun, tmax);                                          \
      float sc = __builtin_amdgcn_exp2f(mrun - mnew);                          \
      lrun *= sc;                                                              \
      _Pragma("unroll")                                                        \
      for (int ds = 0; ds < 4; ++ds) Oc[ds] = Oc[ds] * sc;                     \
      mrun = mnew;                                                             \
    }                                                                          \
    float tsum = 0.f;                                                          \
    _Pragma("unroll")                                                          \
    for (int ss = 0; ss < 4; ++ss)                                             \
      _Pragma("unroll")                                                        \
      for (int r = 0; r < 4; ++r) {                                            \
        float p = __builtin_amdgcn_exp2f(sv[ss][r] - mrun);                    \
        sv[ss][r] = p;                                                         \
        tsum += p;                                                             \
      }                                                                        \
    tsum += __shfl_xor(tsum, 16);                                              \
    tsum += __shfl_xor(tsum, 32);                                              \
    lrun += tsum;                                                              \
    /* ---- P^T -> per-wave swizzled LDS (b64: adjacent sp pairs) ---- */      \
    _Pragma("unroll")                                                          \
    for (int ss = 0; ss < 4; ++ss) {                                           \
      uint2 val;                                                               \
      val.x = cvtpk(sv[ss][0], sv[ss][1]);                                     \
      val.y = cvtpk(sv[ss][2], sv[ss][3]);                                     \
      int sp = ss * 8 + g * 2;                                                 \
      *(uint2*)&Pb[w][c * 32 + (((sp >> 2) ^ (c & 7)) << 2) + (sp & 3)] = val; \
    }                                                                          \
    /* ---- PV: O^T[d][q] += V^T x P^T ---- */                                 \
    __builtin_amdgcn_s_setprio(1);                                             \
    _Pragma("unroll")                                                          \
    for (int w2 = 0; w2 < 2; ++w2) {                                           \
      bf16x8 pf = __builtin_bit_cast(bf16x8,                                   \
          *(const u32x4*)&Pb[w][c * 32 + (((w2 * 4 + g) ^ (c & 7)) << 2)]);    \
      _Pragma("unroll")                                                        \
      for (int ds = 0; ds < 4; ++ds) {                                         \
        bf16x8 vf = __builtin_bit_cast(bf16x8,                                 \
            *(const u32x4*)&Vts[BUF][(ds * 16 + c) * 64 +                      \
                                     (((w2 * 4 + g) ^ (c & 7)) * 8)]);         \
        Oc[ds] = __builtin_amdgcn_mfma_f32_16x16x32_bf16(vf, pf, Oc[ds],       \
                                                         0, 0, 0);             \
      }                                                                        \
    }                                                                          \
    __builtin_amdgcn_s_setprio(0);                                             \
    __syncthreads();                                                           \
    if (STG) {                                                                 \
      pw0 = npw0; pw1 = npw1;                                                  \
      if constexpr (USE_CM) {                                                  \
        _Pragma("unroll")                                                      \
        for (int ss = 0; ss < 4; ++ss) cm[ss] = ncm[ss];                       \
      }                                                                        \
    }                                                                          \
  }

  for (int tt = 0; tt < 14; tt += 2) {
    BODY(0, tt, 1)
    BODY(1, tt + 1, 1)
  }
  BODY(0, 14, 1)
  BODY(1, 15, 0)
#undef BODY

  // ---- epilogue: divide by l, store O (lane holds d = ds*16+4g+r, q = c) ----
  float inv = 1.0f / lrun;
  float* orow = out + ((n * 1024 + l) * 16 + h) * 64;
#pragma unroll
  for (int ds = 0; ds < 4; ++ds) {
    float4 o;
    o.x = Oc[ds][0] * inv; o.y = Oc[ds][1] * inv;
    o.z = Oc[ds][2] * inv; o.w = Oc[ds][3] * inv;
    *(float4*)(orow + ds * 16 + g * 4) = o;
  }
}

extern "C" void kernel_launch(void* const* d_in, const int* in_sizes, int n_in,
                              void* d_out, int out_size, void* d_ws, size_t ws_size,
                              hipStream_t stream) {
  const float* Q    = (const float*)d_in[0];
  const float* K    = (const float*)d_in[1];
  const float* V    = (const float*)d_in[2];
  const float* mask = (const float*)d_in[3];
  const float* klm  = (const float*)d_in[4];
  const float* ptab = (const float*)d_in[5];
  const int*   pos  = (const int*)d_in[6];
  float* out = (float*)d_out;

  char* ws = (char*)d_ws;
  unsigned int*   pospk = (unsigned int*)ws;                               // 512 KB
  unsigned short* Kp    = (unsigned short*)(ws + (1 << 19));               // 8 MB
  unsigned short* Vt    = (unsigned short*)(ws + (1 << 19) + (8 << 20));   // 8 MB
  unsigned short* CM    = (unsigned short*)(ws + (1 << 19) + (16 << 20));  // 8 MB
  const size_t need_cm = (size_t)(1 << 19) + (size_t)(24 << 20);
  const bool use_cm = ws_size >= need_cm;

  k_prep<<<18688, 256, 0, stream>>>(pos, pospk, K, Kp, V, Vt, mask, klm, CM,
                                    use_cm ? 1 : 0);
  if (use_cm) {
    k_attn<true><<<1024, 256, 0, stream>>>(Q, mask, klm, ptab, pospk, Kp, Vt, CM, out);
  } else {
    k_attn<false><<<1024, 256, 0, stream>>>(Q, mask, klm, ptab, pospk, Kp, Vt, nullptr, out);
  }
}

// Round 4
// 77.508 us; speedup vs baseline: 1.1763x; 1.0322x over previous
//
#include <hip/hip_runtime.h>

// FullAttention_Spatial: N=4, L=S=1024, H=16, E=D=64, NUM_POS=2, fp32 in/out.
//
// score = temp*(QK + attn_mask[l,s] + klm[n,s]) + pos_table[pos[n,l,s]][h]
// pos in {0,1} => bias = T0[h] + bit*(T1[h]-T0[h]); T0 cancels in softmax.
// Log2-domain softmax; Q pre-scaled by temp2 = temp*log2e.
//
// R3: 32x32x16 MFMA, 32 q/wave, 128 q/block, grid 512. P stays in registers
// (v_permlane32_swap_b32 half-exchange), no P LDS buffer. 2-phase dbuf K/V
// staging via global_load_lds(16B). LDS read addresses loop-invariant.
//
// Layouts (m74/m101): C of 32x32: col=lane&31, row=(reg&3)+8*(reg>>2)+4*(lane>>5).
// A-frag: row=lane&31, k=8*(lane>>5)+j. B-frag: col=lane&31, k=8*(lane>>5)+j.

typedef __attribute__((ext_vector_type(8))) __bf16 bf16x8;
typedef __attribute__((ext_vector_type(16))) float f32x16;
typedef __attribute__((ext_vector_type(4))) unsigned int u32x4;

#define TEMP2 (0.125f * 1.4426950408889634f)
#define LG2E 1.4426950408889634f

static __device__ __forceinline__ unsigned short f2bf(float x) {
  unsigned int u = __builtin_bit_cast(unsigned int, x);
  u += 0x7FFFu + ((u >> 16) & 1u);
  return (unsigned short)(u >> 16);
}
static __device__ __forceinline__ unsigned int cvtpk(float lo, float hi) {
  unsigned int r;
  asm("v_cvt_pk_bf16_f32 %0, %1, %2" : "=v"(r) : "v"(lo), "v"(hi));
  return r;
}
static __device__ __forceinline__ void gload16(const void* g, void* l) {
  __builtin_amdgcn_global_load_lds((const __attribute__((address_space(1))) void*)g,
                                   (__attribute__((address_space(3))) void*)l, 16, 0, 0);
}
// After: a = {a.lo32, b.lo32}, b = {a.hi32, b.hi32}
static __device__ __forceinline__ void plswap(unsigned int& a, unsigned int& b) {
  asm("v_permlane32_swap_b32 %0, %1" : "+v"(a), "+v"(b));
}

// ---------------- fused prepass (unchanged from R2) ----------------
__global__ __launch_bounds__(256) void k_prep(
    const int* __restrict__ pos, unsigned int* __restrict__ pospk,
    const float* __restrict__ K, unsigned short* __restrict__ Kp,
    const float* __restrict__ V, unsigned short* __restrict__ Vt,
    const float* __restrict__ mask, const float* __restrict__ klm,
    unsigned short* __restrict__ CM, int use_cm) {
  __shared__ float ld[64][65];
  int b = blockIdx.x;
  int tid = threadIdx.x;
  if (b < 256) {
    int idx = b * 256 + tid;
    int s = (idx >> 4) & 1023;
    const float* src = K + idx * 64;
    unsigned short row[64];
#pragma unroll
    for (int j = 0; j < 16; ++j) {
      float4 v = *(const float4*)(src + j * 4);
      row[j*4+0] = f2bf(v.x); row[j*4+1] = f2bf(v.y);
      row[j*4+2] = f2bf(v.z); row[j*4+3] = f2bf(v.w);
    }
    int n = idx >> 14, h = idx & 15;
    unsigned short* dst = Kp + ((n * 16 + h) * 1024 + s) * 64;
#pragma unroll
    for (int bb = 0; bb < 8; ++bb) {
      int pb = bb ^ (s & 7);
      *(u32x4*)(dst + pb * 8) = *(const u32x4*)(&row[bb * 8]);
    }
  } else if (b < 1280) {
    int vb = b - 256;
    int t = vb & 15, h = (vb >> 4) & 15, n = vb >> 8;
    {
      int s = tid >> 2, dq = (tid & 3) * 16;
      const float* src = V + ((n * 1024 + t * 64 + s) * 16 + h) * 64 + dq;
#pragma unroll
      for (int j = 0; j < 4; ++j) {
        float4 v = *(const float4*)(src + j * 4);
        ld[s][dq + j*4 + 0] = v.x; ld[s][dq + j*4 + 1] = v.y;
        ld[s][dq + j*4 + 2] = v.z; ld[s][dq + j*4 + 3] = v.w;
      }
    }
    __syncthreads();
    {
      int d = tid >> 2, sq = (tid & 3) * 16;
      unsigned short vals[16];
#pragma unroll
      for (int k = 0; k < 16; ++k) vals[k] = f2bf(ld[sq + k][d]);
      unsigned short* dst = Vt + ((n * 16 + h) * 64 + d) * 1024 + t * 64;
#pragma unroll
      for (int cb = 0; cb < 2; ++cb) {
        int blk = (sq >> 3) + cb;
        int pb = blk ^ (d & 7);
        *(u32x4*)(dst + pb * 8) = *(const u32x4*)(&vals[cb * 8]);
      }
    }
  } else if (b < 2304) {
    if (!use_cm) return;
    int flat = (b - 1280) * 256 * 16 + tid * 16;
    int n = flat >> 20, l = (flat >> 10) & 1023, s0 = flat & 1023;
    const float* mrow = mask + l * 1024 + s0;
    const float* krow = klm + n * 1024 + s0;
    unsigned int o[8];
#pragma unroll
    for (int j = 0; j < 4; ++j) {
      float4 mv = *(const float4*)(mrow + j * 4);
      float4 kv = *(const float4*)(krow + j * 4);
      o[j*2+0] = cvtpk((mv.x + kv.x) * TEMP2, (mv.y + kv.y) * TEMP2);
      o[j*2+1] = cvtpk((mv.z + kv.z) * TEMP2, (mv.w + kv.w) * TEMP2);
    }
    *(u32x4*)(CM + flat)     = *(const u32x4*)(&o[0]);
    *(u32x4*)(CM + flat + 8) = *(const u32x4*)(&o[4]);
  } else {
    int gi = (b - 2304) * 256 + tid;
    int v = pos[gi];
    unsigned long long m = __ballot(v & 1);
    int lane = tid & 63;
    if (lane == 0) pospk[gi >> 5] = (unsigned int)m;
    else if (lane == 32) pospk[gi >> 5] = (unsigned int)(m >> 32);
  }
}

// ---------------- main flash-attention kernel ----------------
// grid 512 = (lblk<<6) | (h<<2) | n ; 4 waves x 32 q-rows = 128 q/block.
template <bool USE_CM>
__global__ __launch_bounds__(256, 2) void k_attn(
    const float* __restrict__ Q, const float* __restrict__ mask,
    const float* __restrict__ klm, const float* __restrict__ ptab,
    const unsigned int* __restrict__ pospk,
    const unsigned short* __restrict__ Kp, const unsigned short* __restrict__ Vt,
    const unsigned short* __restrict__ CMp,
    float* __restrict__ out) {
  __shared__ __align__(16) unsigned short Kt[2][4096];   // [64 s][64 e] swizzled
  __shared__ __align__(16) unsigned short Vts[2][4096];  // [64 d][64 s] swizzled

  int bid = blockIdx.x;
  int n = bid & 3, h = (bid >> 2) & 15, lblk = bid >> 6;
  int tid = threadIdx.x;
  int w = tid >> 6, lane = tid & 63;
  int l31 = lane & 31, h5 = lane >> 5;
  int l = lblk * 128 + w * 32 + l31;   // this lane's q-row (global)

  // Q fragments (B of swapped QK^T), pre-scaled by temp2
  const float* qrow = Q + ((n * 1024 + l) * 16 + h) * 64;
  bf16x8 qf[4];
#pragma unroll
  for (int ke = 0; ke < 4; ++ke) {
    float4 a = *(const float4*)(qrow + ke * 16 + h5 * 8);
    float4 b = *(const float4*)(qrow + ke * 16 + h5 * 8 + 4);
    u32x4 pk;
    pk[0] = cvtpk(a.x * TEMP2, a.y * TEMP2);
    pk[1] = cvtpk(a.z * TEMP2, a.w * TEMP2);
    pk[2] = cvtpk(b.x * TEMP2, b.y * TEMP2);
    pk[3] = cvtpk(b.z * TEMP2, b.w * TEMP2);
    qf[ke] = __builtin_bit_cast(bf16x8, pk);
  }
  const float delta2 = (ptab[16 + h] - ptab[h]) * LG2E;

  float mrun = -1e30f, lrun = 0.f;
  f32x16 Oc0 = {0,0,0,0,0,0,0,0,0,0,0,0,0,0,0,0};
  f32x16 Oc1 = {0,0,0,0,0,0,0,0,0,0,0,0,0,0,0,0};

  const unsigned short* KpB = Kp + (n * 16 + h) * 65536;
  const unsigned short* VtB = Vt + (n * 16 + h) * 65536;
  const unsigned short* CMb = USE_CM ? (CMp + (n * 1024 + l) * 1024) : nullptr;
  const float* mrowB = mask + l * 1024;
  const float* krowB = klm + n * 1024;
  const unsigned int* posB = pospk + (n * 1024 + l) * 32;

  // loop-invariant LDS read offsets (shorts): col slot per K-step, row base
  const int x7 = l31 & 7;
  const int co0 = ((0 + h5) ^ x7) * 8;
  const int co1 = ((2 + h5) ^ x7) * 8;
  const int co2 = ((4 + h5) ^ x7) * 8;
  const int co3 = ((6 + h5) ^ x7) * 8;
  const int rb = l31 * 64;
  const int h4 = h5 * 4;

  // staging addresses
  const unsigned short* kS = KpB + w * 1024 + lane * 8;
  const unsigned short* vS = VtB + (w * 16 + (lane >> 3)) * 1024 + (lane & 7) * 8;
  const int kD = w * 1024 + lane * 8;   // LDS dst (shorts), +512 for j=1

#define LDK(BUF, OFF) __builtin_bit_cast(bf16x8, *(const u32x4*)&Kt[BUF][OFF])
#define LDV(BUF, OFF) __builtin_bit_cast(bf16x8, *(const u32x4*)&Vts[BUF][OFF])

  // ---- prologue: stage tile 0 into buf 0; prefetch pos/bias for tile 0 ----
  gload16(kS, &Kt[0][kD]);
  gload16(kS + 512, &Kt[0][kD + 512]);
  gload16(vS, &Vts[0][kD]);
  gload16(vS + 8192, &Vts[0][kD + 512]);
  uint2 pwv = *(const uint2*)(posB);
  uint2 cmq[8];
  if constexpr (USE_CM) {
#pragma unroll
    for (int q8 = 0; q8 < 8; ++q8)
      cmq[q8] = *(const uint2*)(CMb + (q8 >> 2) * 32 + (q8 & 3) * 8 + h4);
  }
  __syncthreads();

#define BODY(BUF, T, STG)                                                      \
  {                                                                            \
    uint2 npwv = {0, 0};                                                       \
    uint2 ncmq[8];                                                             \
    if (STG) {                                                                 \
      const int Tn = (T) + 1;                                                  \
      gload16(kS + Tn * 4096, &Kt[BUF ^ 1][kD]);                               \
      gload16(kS + Tn * 4096 + 512, &Kt[BUF ^ 1][kD + 512]);                   \
      gload16(vS + Tn * 64, &Vts[BUF ^ 1][kD]);                                \
      gload16(vS + Tn * 64 + 8192, &Vts[BUF ^ 1][kD + 512]);                   \
      npwv = *(const uint2*)(posB + Tn * 2);                                   \
      if constexpr (USE_CM) {                                                  \
        _Pragma("unroll")                                                      \
        for (int q8 = 0; q8 < 8; ++q8)                                         \
          ncmq[q8] = *(const uint2*)(CMb + Tn * 64 + (q8 >> 2) * 32 +          \
                                     (q8 & 3) * 8 + h4);                       \
      }                                                                        \
    }                                                                          \
    /* ---- QK^T: S^T[s][q], two 32-s blocks, 4 K-steps each ---- */           \
    f32x16 sv0 = {0,0,0,0,0,0,0,0,0,0,0,0,0,0,0,0};                            \
    f32x16 sv1 = {0,0,0,0,0,0,0,0,0,0,0,0,0,0,0,0};                            \
    __builtin_amdgcn_s_setprio(1);                                             \
    sv0 = __builtin_amdgcn_mfma_f32_32x32x16_bf16(LDK(BUF, rb + co0), qf[0], sv0, 0, 0, 0); \
    sv1 = __builtin_amdgcn_mfma_f32_32x32x16_bf16(LDK(BUF, rb + 2048 + co0), qf[0], sv1, 0, 0, 0); \
    sv0 = __builtin_amdgcn_mfma_f32_32x32x16_bf16(LDK(BUF, rb + co1), qf[1], sv0, 0, 0, 0); \
    sv1 = __builtin_amdgcn_mfma_f32_32x32x16_bf16(LDK(BUF, rb + 2048 + co1), qf[1], sv1, 0, 0, 0); \
    sv0 = __builtin_amdgcn_mfma_f32_32x32x16_bf16(LDK(BUF, rb + co2), qf[2], sv0, 0, 0, 0); \
    sv1 = __builtin_amdgcn_mfma_f32_32x32x16_bf16(LDK(BUF, rb + 2048 + co2), qf[2], sv1, 0, 0, 0); \
    sv0 = __builtin_amdgcn_mfma_f32_32x32x16_bf16(LDK(BUF, rb + co3), qf[3], sv0, 0, 0, 0); \
    sv1 = __builtin_amdgcn_mfma_f32_32x32x16_bf16(LDK(BUF, rb + 2048 + co3), qf[3], sv1, 0, 0, 0); \
    __builtin_amdgcn_s_setprio(0);                                             \
    /* ---- bias: CM + pos bit, per reg s=(i)+8*r2+4*h5 (+32 for sv1) ---- */  \
    {                                                                          \
      unsigned pws0 = pwv.x >> h4;                                             \
      unsigned pws1 = pwv.y >> h4;                                             \
      _Pragma("unroll")                                                        \
      for (int r2 = 0; r2 < 4; ++r2) {                                         \
        float b0[4], b1[4];                                                    \
        if constexpr (USE_CM) {                                                \
          b0[0] = __builtin_bit_cast(float, cmq[r2].x << 16);                  \
          b0[1] = __builtin_bit_cast(float, cmq[r2].x & 0xFFFF0000u);          \
          b0[2] = __builtin_bit_cast(float, cmq[r2].y << 16);                  \
          b0[3] = __builtin_bit_cast(float, cmq[r2].y & 0xFFFF0000u);          \
          b1[0] = __builtin_bit_cast(float, cmq[4 + r2].x << 16);              \
          b1[1] = __builtin_bit_cast(float, cmq[4 + r2].x & 0xFFFF0000u);      \
          b1[2] = __builtin_bit_cast(float, cmq[4 + r2].y << 16);              \
          b1[3] = __builtin_bit_cast(float, cmq[4 + r2].y & 0xFFFF0000u);      \
        } else {                                                               \
          float4 mv0 = *(const float4*)(mrowB + (T) * 64 + r2 * 8 + h4);       \
          float4 kv0 = *(const float4*)(krowB + (T) * 64 + r2 * 8 + h4);       \
          float4 mv1 = *(const float4*)(mrowB + (T) * 64 + 32 + r2 * 8 + h4);  \
          float4 kv1 = *(const float4*)(krowB + (T) * 64 + 32 + r2 * 8 + h4);  \
          b0[0] = (mv0.x + kv0.x) * TEMP2; b0[1] = (mv0.y + kv0.y) * TEMP2;    \
          b0[2] = (mv0.z + kv0.z) * TEMP2; b0[3] = (mv0.w + kv0.w) * TEMP2;    \
          b1[0] = (mv1.x + kv1.x) * TEMP2; b1[1] = (mv1.y + kv1.y) * TEMP2;    \
          b1[2] = (mv1.z + kv1.z) * TEMP2; b1[3] = (mv1.w + kv1.w) * TEMP2;    \
        }                                                                      \
        _Pragma("unroll")                                                      \
        for (int i = 0; i < 4; ++i) {                                          \
          float bit0 = (float)((pws0 >> (r2 * 8 + i)) & 1u);                   \
          float bit1 = (float)((pws1 >> (r2 * 8 + i)) & 1u);                   \
          sv0[r2 * 4 + i] = fmaf(bit0, delta2, sv0[r2 * 4 + i] + b0[i]);       \
          sv1[r2 * 4 + i] = fmaf(bit1, delta2, sv1[r2 * 4 + i] + b1[i]);       \
        }                                                                      \
      }                                                                        \
    }                                                                          \
    /* ---- online softmax (row q: lanes l31, l31+32) ---- */                  \
    {                                                                          \
      float m8[8];                                                             \
      _Pragma("unroll")                                                        \
      for (int i = 0; i < 8; ++i)                                              \
        m8[i] = fmaxf(fmaxf(sv0[2 * i], sv0[2 * i + 1]),                       \
                      fmaxf(sv1[2 * i], sv1[2 * i + 1]));                      \
      float m4a = fmaxf(m8[0], m8[1]), m4b = fmaxf(m8[2], m8[3]);              \
      float m4c = fmaxf(m8[4], m8[5]), m4d = fmaxf(m8[6], m8[7]);              \
      float tmax = fmaxf(fmaxf(m4a, m4b), fmaxf(m4c, m4d));                    \
      tmax = fmaxf(tmax, __shfl_xor(tmax, 32));                                \
      if (!__all(tmax <= mrun + 4.0f)) {                                       \
        float mnew = fmaxf(mrun, tmax);                                        \
        float sc = __builtin_amdgcn_exp2f(mrun - mnew);                        \
        lrun *= sc;                                                            \
        Oc0 *= sc; Oc1 *= sc;                                                  \
        mrun = mnew;                                                           \
      }                                                                        \
      float s8[8];                                                             \
      _Pragma("unroll")                                                        \
      for (int i = 0; i < 8; ++i) {                                            \
        float p0 = __builtin_amdgcn_exp2f(sv0[2 * i] - mrun);                  \
        float p1 = __builtin_amdgcn_exp2f(sv0[2 * i + 1] - mrun);              \
        float p2 = __builtin_amdgcn_exp2f(sv1[2 * i] - mrun);                  \
        float p3 = __builtin_amdgcn_exp2f(sv1[2 * i + 1] - mrun);              \
        sv0[2 * i] = p0; sv0[2 * i + 1] = p1;                                  \
        sv1[2 * i] = p2; sv1[2 * i + 1] = p3;                                  \
        s8[i] = (p0 + p1) + (p2 + p3);                                         \
      }                                                                        \
      float s4a = s8[0] + s8[1], s4b = s8[2] + s8[3];                          \
      float s4c = s8[4] + s8[5], s4d = s8[6] + s8[7];                          \
      float tsum = (s4a + s4b) + (s4c + s4d);                                  \
      tsum += __shfl_xor(tsum, 32);                                            \
      lrun += tsum;                                                            \
    }                                                                          \
    /* ---- pack P to bf16 words W[B5][R2][i] ---- */                          \
    unsigned w000 = cvtpk(sv0[0], sv0[1]),   w001 = cvtpk(sv0[2], sv0[3]);     \
    unsigned w010 = cvtpk(sv0[4], sv0[5]),   w011 = cvtpk(sv0[6], sv0[7]);     \
    unsigned w020 = cvtpk(sv0[8], sv0[9]),   w021 = cvtpk(sv0[10], sv0[11]);   \
    unsigned w030 = cvtpk(sv0[12], sv0[13]), w031 = cvtpk(sv0[14], sv0[15]);   \
    unsigned w100 = cvtpk(sv1[0], sv1[1]),   w101 = cvtpk(sv1[2], sv1[3]);     \
    unsigned w110 = cvtpk(sv1[4], sv1[5]),   w111 = cvtpk(sv1[6], sv1[7]);     \
    unsigned w120 = cvtpk(sv1[8], sv1[9]),   w121 = cvtpk(sv1[10], sv1[11]);   \
    unsigned w130 = cvtpk(sv1[12], sv1[13]), w131 = cvtpk(sv1[14], sv1[15]);   \
    /* ---- PV: O^T[d][q] += V^T x P^T, pf via permlane32_swap ---- */         \
    __builtin_amdgcn_s_setprio(1);                                             \
    {                                                                          \
      u32x4 pfw;                                                               \
      plswap(w000, w010); plswap(w001, w011);                                  \
      pfw[0] = w000; pfw[1] = w001; pfw[2] = w010; pfw[3] = w011;              \
      bf16x8 pf = __builtin_bit_cast(bf16x8, pfw);                             \
      Oc0 = __builtin_amdgcn_mfma_f32_32x32x16_bf16(LDV(BUF, rb + co0), pf, Oc0, 0, 0, 0); \
      Oc1 = __builtin_amdgcn_mfma_f32_32x32x16_bf16(LDV(BUF, rb + 2048 + co0), pf, Oc1, 0, 0, 0); \
      plswap(w020, w030); plswap(w021, w031);                                  \
      pfw[0] = w020; pfw[1] = w021; pfw[2] = w030; pfw[3] = w031;              \
      pf = __builtin_bit_cast(bf16x8, pfw);                                    \
      Oc0 = __builtin_amdgcn_mfma_f32_32x32x16_bf16(LDV(BUF, rb + co1), pf, Oc0, 0, 0, 0); \
      Oc1 = __builtin_amdgcn_mfma_f32_32x32x16_bf16(LDV(BUF, rb + 2048 + co1), pf, Oc1, 0, 0, 0); \
      plswap(w100, w110); plswap(w101, w111);                                  \
      pfw[0] = w100; pfw[1] = w101; pfw[2] = w110; pfw[3] = w111;              \
      pf = __builtin_bit_cast(bf16x8, pfw);                                    \
      Oc0 = __builtin_amdgcn_mfma_f32_32x32x16_bf16(LDV(BUF, rb + co2), pf, Oc0, 0, 0, 0); \
      Oc1 = __builtin_amdgcn_mfma_f32_32x32x16_bf16(LDV(BUF, rb + 2048 + co2), pf, Oc1, 0, 0, 0); \
      plswap(w120, w130); plswap(w121, w131);                                  \
      pfw[0] = w120; pfw[1] = w121; pfw[2] = w130; pfw[3] = w131;              \
      pf = __builtin_bit_cast(bf16x8, pfw);                                    \
      Oc0 = __builtin_amdgcn_mfma_f32_32x32x16_bf16(LDV(BUF, rb + co3), pf, Oc0, 0, 0, 0); \
      Oc1 = __builtin_amdgcn_mfma_f32_32x32x16_bf16(LDV(BUF, rb + 2048 + co3), pf, Oc1, 0, 0, 0); \
    }                                                                          \
    __builtin_amdgcn_s_setprio(0);                                             \
    __syncthreads();                                                           \
    if (STG) {                                                                 \
      pwv = npwv;                                                              \
      if constexpr (USE_CM) {                                                  \
        _Pragma("unroll")                                                      \
        for (int q8 = 0; q8 < 8; ++q8) cmq[q8] = ncmq[q8];                     \
      }                                                                        \
    }                                                                          \
  }

  for (int tt = 0; tt < 14; tt += 2) {
    BODY(0, tt, 1)
    BODY(1, tt + 1, 1)
  }
  BODY(0, 14, 1)
  BODY(1, 15, 0)
#undef BODY
#undef LDK
#undef LDV

  // ---- epilogue: /l, store O^T -> out[n][q][h][d] ----
  float inv = 1.0f / lrun;
  float* orow = out + ((n * 1024 + l) * 16 + h) * 64;
#pragma unroll
  for (int r2 = 0; r2 < 4; ++r2) {
    float4 o;
    o.x = Oc0[4 * r2 + 0] * inv; o.y = Oc0[4 * r2 + 1] * inv;
    o.z = Oc0[4 * r2 + 2] * inv; o.w = Oc0[4 * r2 + 3] * inv;
    *(float4*)(orow + r2 * 8 + h4) = o;
    o.x = Oc1[4 * r2 + 0] * inv; o.y = Oc1[4 * r2 + 1] * inv;
    o.z = Oc1[4 * r2 + 2] * inv; o.w = Oc1[4 * r2 + 3] * inv;
    *(float4*)(orow + 32 + r2 * 8 + h4) = o;
  }
}

extern "C" void kernel_launch(void* const* d_in, const int* in_sizes, int n_in,
                              void* d_out, int out_size, void* d_ws, size_t ws_size,
                              hipStream_t stream) {
  const float* Q    = (const float*)d_in[0];
  const float* K    = (const float*)d_in[1];
  const float* V    = (const float*)d_in[2];
  const float* mask = (const float*)d_in[3];
  const float* klm  = (const float*)d_in[4];
  const float* ptab = (const float*)d_in[5];
  const int*   pos  = (const int*)d_in[6];
  float* out = (float*)d_out;

  char* ws = (char*)d_ws;
  unsigned int*   pospk = (unsigned int*)ws;                               // 512 KB
  unsigned short* Kp    = (unsigned short*)(ws + (1 << 19));               // 8 MB
  unsigned short* Vt    = (unsigned short*)(ws + (1 << 19) + (8 << 20));   // 8 MB
  unsigned short* CM    = (unsigned short*)(ws + (1 << 19) + (16 << 20));  // 8 MB
  const size_t need_cm = (size_t)(1 << 19) + (size_t)(24 << 20);
  const bool use_cm = ws_size >= need_cm;

  k_prep<<<18688, 256, 0, stream>>>(pos, pospk, K, Kp, V, Vt, mask, klm, CM,
                                    use_cm ? 1 : 0);
  if (use_cm) {
    k_attn<true><<<512, 256, 0, stream>>>(Q, mask, klm, ptab, pospk, Kp, Vt, CM, out);
  } else {
    k_attn<false><<<512, 256, 0, stream>>>(Q, mask, klm, ptab, pospk, Kp, Vt, nullptr, out);
  }
}

// Round 5
// 73.312 us; speedup vs baseline: 1.2436x; 1.0572x over previous
//
#include <hip/hip_runtime.h>

// FullAttention_Spatial: N=4, L=S=1024, H=16, E=D=64, NUM_POS=2, fp32 in/out.
//
// score = temp*(QK + attn_mask[l,s] + klm[n,s]) + pos_table[pos[n,l,s]][h]
// pos in {0,1} => bias = T0[h] + bit*(T1[h]-T0[h]); T0 cancels in softmax.
// Log2-domain softmax; Q pre-scaled by temp2 = temp*log2e.
//
// R4: cross-tile pipeline. body(i) = {stage(i+1); QK^T(i) || PV(i-1) as one
// 16-MFMA block; bias+softmax(i); pack P(i) -> 4 u32x4 frags (plswap'd)}.
// K dbuf x2, V dbuf x3 (read i-1 / ready i / stage i+1). One barrier/body.
// 32x32x16 MFMA, 32 q/wave, 128 q/block, grid 512.
//
// Layouts (m74/m101): C of 32x32: col=lane&31, row=(reg&3)+8*(reg>>2)+4*(lane>>5).
// A-frag: row=lane&31, k=8*(lane>>5)+j. B-frag: col=lane&31, k=8*(lane>>5)+j.

typedef __attribute__((ext_vector_type(8))) __bf16 bf16x8;
typedef __attribute__((ext_vector_type(16))) float f32x16;
typedef __attribute__((ext_vector_type(4))) unsigned int u32x4;

#define TEMP2 (0.125f * 1.4426950408889634f)
#define LG2E 1.4426950408889634f

static __device__ __forceinline__ unsigned short f2bf(float x) {
  unsigned int u = __builtin_bit_cast(unsigned int, x);
  u += 0x7FFFu + ((u >> 16) & 1u);
  return (unsigned short)(u >> 16);
}
static __device__ __forceinline__ unsigned int cvtpk(float lo, float hi) {
  unsigned int r;
  asm("v_cvt_pk_bf16_f32 %0, %1, %2" : "=v"(r) : "v"(lo), "v"(hi));
  return r;
}
static __device__ __forceinline__ void gload16(const void* g, void* l) {
  __builtin_amdgcn_global_load_lds((const __attribute__((address_space(1))) void*)g,
                                   (__attribute__((address_space(3))) void*)l, 16, 0, 0);
}
// After: a = {a.lo32, b.lo32}, b = {a.hi32, b.hi32}
static __device__ __forceinline__ void plswap(unsigned int& a, unsigned int& b) {
  asm("v_permlane32_swap_b32 %0, %1" : "+v"(a), "+v"(b));
}

// ---------------- fused prepass (unchanged) ----------------
__global__ __launch_bounds__(256) void k_prep(
    const int* __restrict__ pos, unsigned int* __restrict__ pospk,
    const float* __restrict__ K, unsigned short* __restrict__ Kp,
    const float* __restrict__ V, unsigned short* __restrict__ Vt,
    const float* __restrict__ mask, const float* __restrict__ klm,
    unsigned short* __restrict__ CM, int use_cm) {
  __shared__ float ld[64][65];
  int b = blockIdx.x;
  int tid = threadIdx.x;
  if (b < 256) {
    int idx = b * 256 + tid;
    int s = (idx >> 4) & 1023;
    const float* src = K + idx * 64;
    unsigned short row[64];
#pragma unroll
    for (int j = 0; j < 16; ++j) {
      float4 v = *(const float4*)(src + j * 4);
      row[j*4+0] = f2bf(v.x); row[j*4+1] = f2bf(v.y);
      row[j*4+2] = f2bf(v.z); row[j*4+3] = f2bf(v.w);
    }
    int n = idx >> 14, h = idx & 15;
    unsigned short* dst = Kp + ((n * 16 + h) * 1024 + s) * 64;
#pragma unroll
    for (int bb = 0; bb < 8; ++bb) {
      int pb = bb ^ (s & 7);
      *(u32x4*)(dst + pb * 8) = *(const u32x4*)(&row[bb * 8]);
    }
  } else if (b < 1280) {
    int vb = b - 256;
    int t = vb & 15, h = (vb >> 4) & 15, n = vb >> 8;
    {
      int s = tid >> 2, dq = (tid & 3) * 16;
      const float* src = V + ((n * 1024 + t * 64 + s) * 16 + h) * 64 + dq;
#pragma unroll
      for (int j = 0; j < 4; ++j) {
        float4 v = *(const float4*)(src + j * 4);
        ld[s][dq + j*4 + 0] = v.x; ld[s][dq + j*4 + 1] = v.y;
        ld[s][dq + j*4 + 2] = v.z; ld[s][dq + j*4 + 3] = v.w;
      }
    }
    __syncthreads();
    {
      int d = tid >> 2, sq = (tid & 3) * 16;
      unsigned short vals[16];
#pragma unroll
      for (int k = 0; k < 16; ++k) vals[k] = f2bf(ld[sq + k][d]);
      unsigned short* dst = Vt + ((n * 16 + h) * 64 + d) * 1024 + t * 64;
#pragma unroll
      for (int cb = 0; cb < 2; ++cb) {
        int blk = (sq >> 3) + cb;
        int pb = blk ^ (d & 7);
        *(u32x4*)(dst + pb * 8) = *(const u32x4*)(&vals[cb * 8]);
      }
    }
  } else if (b < 2304) {
    if (!use_cm) return;
    int flat = (b - 1280) * 256 * 16 + tid * 16;
    int n = flat >> 20, l = (flat >> 10) & 1023, s0 = flat & 1023;
    const float* mrow = mask + l * 1024 + s0;
    const float* krow = klm + n * 1024 + s0;
    unsigned int o[8];
#pragma unroll
    for (int j = 0; j < 4; ++j) {
      float4 mv = *(const float4*)(mrow + j * 4);
      float4 kv = *(const float4*)(krow + j * 4);
      o[j*2+0] = cvtpk((mv.x + kv.x) * TEMP2, (mv.y + kv.y) * TEMP2);
      o[j*2+1] = cvtpk((mv.z + kv.z) * TEMP2, (mv.w + kv.w) * TEMP2);
    }
    *(u32x4*)(CM + flat)     = *(const u32x4*)(&o[0]);
    *(u32x4*)(CM + flat + 8) = *(const u32x4*)(&o[4]);
  } else {
    int gi = (b - 2304) * 256 + tid;
    int v = pos[gi];
    unsigned long long m = __ballot(v & 1);
    int lane = tid & 63;
    if (lane == 0) pospk[gi >> 5] = (unsigned int)m;
    else if (lane == 32) pospk[gi >> 5] = (unsigned int)(m >> 32);
  }
}

// ---------------- main flash-attention kernel ----------------
// grid 512 = (lblk<<6) | (h<<2) | n ; 4 waves x 32 q-rows = 128 q/block.
template <bool USE_CM>
__global__ __launch_bounds__(256, 2) void k_attn(
    const float* __restrict__ Q, const float* __restrict__ mask,
    const float* __restrict__ klm, const float* __restrict__ ptab,
    const unsigned int* __restrict__ pospk,
    const unsigned short* __restrict__ Kp, const unsigned short* __restrict__ Vt,
    const unsigned short* __restrict__ CMp,
    float* __restrict__ out) {
  __shared__ __align__(16) unsigned short Kt[2][4096];   // [64 s][64 e] swizzled
  __shared__ __align__(16) unsigned short Vts[3][4096];  // [64 d][64 s] swizzled

  int bid = blockIdx.x;
  int n = bid & 3, h = (bid >> 2) & 15, lblk = bid >> 6;
  int tid = threadIdx.x;
  int w = tid >> 6, lane = tid & 63;
  int l31 = lane & 31, h5 = lane >> 5;
  int l = lblk * 128 + w * 32 + l31;   // this lane's q-row (global)

  // Q fragments (B of swapped QK^T), pre-scaled by temp2
  const float* qrow = Q + ((n * 1024 + l) * 16 + h) * 64;
  bf16x8 qf[4];
#pragma unroll
  for (int ke = 0; ke < 4; ++ke) {
    float4 a = *(const float4*)(qrow + ke * 16 + h5 * 8);
    float4 b = *(const float4*)(qrow + ke * 16 + h5 * 8 + 4);
    u32x4 pk;
    pk[0] = cvtpk(a.x * TEMP2, a.y * TEMP2);
    pk[1] = cvtpk(a.z * TEMP2, a.w * TEMP2);
    pk[2] = cvtpk(b.x * TEMP2, b.y * TEMP2);
    pk[3] = cvtpk(b.z * TEMP2, b.w * TEMP2);
    qf[ke] = __builtin_bit_cast(bf16x8, pk);
  }
  const float delta2 = (ptab[16 + h] - ptab[h]) * LG2E;

  float mrun = -1e30f, lrun = 0.f;
  f32x16 Oc0 = {0,0,0,0,0,0,0,0,0,0,0,0,0,0,0,0};
  f32x16 Oc1 = {0,0,0,0,0,0,0,0,0,0,0,0,0,0,0,0};
  u32x4 pfA = {0,0,0,0}, pfB = {0,0,0,0}, pfC = {0,0,0,0}, pfD = {0,0,0,0};

  const unsigned short* KpB = Kp + (n * 16 + h) * 65536;
  const unsigned short* VtB = Vt + (n * 16 + h) * 65536;
  const unsigned short* CMb = USE_CM ? (CMp + (n * 1024 + l) * 1024) : nullptr;
  const float* mrowB = mask + l * 1024;
  const float* krowB = klm + n * 1024;
  const unsigned int* posB = pospk + (n * 1024 + l) * 32;

  // loop-invariant LDS read offsets (shorts): col slot per K-step, row base
  const int x7 = l31 & 7;
  const int co0 = ((0 + h5) ^ x7) * 8;
  const int co1 = ((2 + h5) ^ x7) * 8;
  const int co2 = ((4 + h5) ^ x7) * 8;
  const int co3 = ((6 + h5) ^ x7) * 8;
  const int rb = l31 * 64;
  const int h4 = h5 * 4;

  // staging addresses
  const unsigned short* kS = KpB + w * 1024 + lane * 8;
  const unsigned short* vS = VtB + (w * 16 + (lane >> 3)) * 1024 + (lane & 7) * 8;
  const int kD = w * 1024 + lane * 8;   // LDS dst (shorts), +512 for j=1

#define LDK(KB, OFF) __builtin_bit_cast(bf16x8, *(const u32x4*)&Kt[KB][OFF])
#define LDV(VB, OFF) __builtin_bit_cast(bf16x8, *(const u32x4*)&Vts[VB][OFF])

  // ---- prologue: stage tile 0 (K->kb0, V->vb0); prefetch pos/bias tile 0 ----
  gload16(kS, &Kt[0][kD]);
  gload16(kS + 512, &Kt[0][kD + 512]);
  gload16(vS, &Vts[0][kD]);
  gload16(vS + 8192, &Vts[0][kD + 512]);
  uint2 pwv = *(const uint2*)(posB);
  uint2 cmq[8];
  if constexpr (USE_CM) {
#pragma unroll
    for (int q8 = 0; q8 < 8; ++q8)
      cmq[q8] = *(const uint2*)(CMb + (q8 >> 2) * 32 + (q8 & 3) * 8 + h4);
  }
  __syncthreads();

#define BODY(T, KB, KSTG, VRD, VST, DO_PV, STG)                                \
  {                                                                            \
    uint2 npwv = {0, 0};                                                       \
    uint2 ncmq[8];                                                             \
    if (STG) {                                                                 \
      const int Tn = (T) + 1;                                                  \
      gload16(kS + Tn * 4096, &Kt[KSTG][kD]);                                  \
      gload16(kS + Tn * 4096 + 512, &Kt[KSTG][kD + 512]);                      \
      gload16(vS + Tn * 64, &Vts[VST][kD]);                                    \
      gload16(vS + Tn * 64 + 8192, &Vts[VST][kD + 512]);                       \
      npwv = *(const uint2*)(posB + Tn * 2);                                   \
      if constexpr (USE_CM) {                                                  \
        _Pragma("unroll")                                                      \
        for (int q8 = 0; q8 < 8; ++q8)                                         \
          ncmq[q8] = *(const uint2*)(CMb + Tn * 64 + (q8 >> 2) * 32 +          \
                                     (q8 & 3) * 8 + h4);                       \
      }                                                                        \
    }                                                                          \
    /* ---- MFMA block: QK^T(T) and PV(T-1), all independent ---- */           \
    f32x16 sv0 = {0,0,0,0,0,0,0,0,0,0,0,0,0,0,0,0};                            \
    f32x16 sv1 = {0,0,0,0,0,0,0,0,0,0,0,0,0,0,0,0};                            \
    __builtin_amdgcn_s_setprio(1);                                             \
    sv0 = __builtin_amdgcn_mfma_f32_32x32x16_bf16(LDK(KB, rb + co0), qf[0], sv0, 0, 0, 0); \
    sv1 = __builtin_amdgcn_mfma_f32_32x32x16_bf16(LDK(KB, rb + 2048 + co0), qf[0], sv1, 0, 0, 0); \
    if (DO_PV) {                                                               \
      bf16x8 p = __builtin_bit_cast(bf16x8, pfA);                              \
      Oc0 = __builtin_amdgcn_mfma_f32_32x32x16_bf16(LDV(VRD, rb + co0), p, Oc0, 0, 0, 0); \
      Oc1 = __builtin_amdgcn_mfma_f32_32x32x16_bf16(LDV(VRD, rb + 2048 + co0), p, Oc1, 0, 0, 0); \
    }                                                                          \
    sv0 = __builtin_amdgcn_mfma_f32_32x32x16_bf16(LDK(KB, rb + co1), qf[1], sv0, 0, 0, 0); \
    sv1 = __builtin_amdgcn_mfma_f32_32x32x16_bf16(LDK(KB, rb + 2048 + co1), qf[1], sv1, 0, 0, 0); \
    if (DO_PV) {                                                               \
      bf16x8 p = __builtin_bit_cast(bf16x8, pfB);                              \
      Oc0 = __builtin_amdgcn_mfma_f32_32x32x16_bf16(LDV(VRD, rb + co1), p, Oc0, 0, 0, 0); \
      Oc1 = __builtin_amdgcn_mfma_f32_32x32x16_bf16(LDV(VRD, rb + 2048 + co1), p, Oc1, 0, 0, 0); \
    }                                                                          \
    sv0 = __builtin_amdgcn_mfma_f32_32x32x16_bf16(LDK(KB, rb + co2), qf[2], sv0, 0, 0, 0); \
    sv1 = __builtin_amdgcn_mfma_f32_32x32x16_bf16(LDK(KB, rb + 2048 + co2), qf[2], sv1, 0, 0, 0); \
    if (DO_PV) {                                                               \
      bf16x8 p = __builtin_bit_cast(bf16x8, pfC);                              \
      Oc0 = __builtin_amdgcn_mfma_f32_32x32x16_bf16(LDV(VRD, rb + co2), p, Oc0, 0, 0, 0); \
      Oc1 = __builtin_amdgcn_mfma_f32_32x32x16_bf16(LDV(VRD, rb + 2048 + co2), p, Oc1, 0, 0, 0); \
    }                                                                          \
    sv0 = __builtin_amdgcn_mfma_f32_32x32x16_bf16(LDK(KB, rb + co3), qf[3], sv0, 0, 0, 0); \
    sv1 = __builtin_amdgcn_mfma_f32_32x32x16_bf16(LDK(KB, rb + 2048 + co3), qf[3], sv1, 0, 0, 0); \
    if (DO_PV) {                                                               \
      bf16x8 p = __builtin_bit_cast(bf16x8, pfD);                              \
      Oc0 = __builtin_amdgcn_mfma_f32_32x32x16_bf16(LDV(VRD, rb + co3), p, Oc0, 0, 0, 0); \
      Oc1 = __builtin_amdgcn_mfma_f32_32x32x16_bf16(LDV(VRD, rb + 2048 + co3), p, Oc1, 0, 0, 0); \
    }                                                                          \
    __builtin_amdgcn_s_setprio(0);                                             \
    /* ---- bias: CM + pos bit, s=(i)+8*r2+4*h5 (+32 for sv1) ---- */          \
    {                                                                          \
      unsigned pws0 = pwv.x >> h4;                                             \
      unsigned pws1 = pwv.y >> h4;                                             \
      _Pragma("unroll")                                                        \
      for (int r2 = 0; r2 < 4; ++r2) {                                         \
        float b0[4], b1[4];                                                    \
        if constexpr (USE_CM) {                                                \
          b0[0] = __builtin_bit_cast(float, cmq[r2].x << 16);                  \
          b0[1] = __builtin_bit_cast(float, cmq[r2].x & 0xFFFF0000u);          \
          b0[2] = __builtin_bit_cast(float, cmq[r2].y << 16);                  \
          b0[3] = __builtin_bit_cast(float, cmq[r2].y & 0xFFFF0000u);          \
          b1[0] = __builtin_bit_cast(float, cmq[4 + r2].x << 16);              \
          b1[1] = __builtin_bit_cast(float, cmq[4 + r2].x & 0xFFFF0000u);      \
          b1[2] = __builtin_bit_cast(float, cmq[4 + r2].y << 16);              \
          b1[3] = __builtin_bit_cast(float, cmq[4 + r2].y & 0xFFFF0000u);      \
        } else {                                                               \
          float4 mv0 = *(const float4*)(mrowB + (T) * 64 + r2 * 8 + h4);       \
          float4 kv0 = *(const float4*)(krowB + (T) * 64 + r2 * 8 + h4);       \
          float4 mv1 = *(const float4*)(mrowB + (T) * 64 + 32 + r2 * 8 + h4);  \
          float4 kv1 = *(const float4*)(krowB + (T) * 64 + 32 + r2 * 8 + h4);  \
          b0[0] = (mv0.x + kv0.x) * TEMP2; b0[1] = (mv0.y + kv0.y) * TEMP2;    \
          b0[2] = (mv0.z + kv0.z) * TEMP2; b0[3] = (mv0.w + kv0.w) * TEMP2;    \
          b1[0] = (mv1.x + kv1.x) * TEMP2; b1[1] = (mv1.y + kv1.y) * TEMP2;    \
          b1[2] = (mv1.z + kv1.z) * TEMP2; b1[3] = (mv1.w + kv1.w) * TEMP2;    \
        }                                                                      \
        _Pragma("unroll")                                                      \
        for (int i = 0; i < 4; ++i) {                                          \
          float bit0 = (float)((pws0 >> (r2 * 8 + i)) & 1u);                   \
          float bit1 = (float)((pws1 >> (r2 * 8 + i)) & 1u);                   \
          sv0[r2 * 4 + i] = fmaf(bit0, delta2, sv0[r2 * 4 + i] + b0[i]);       \
          sv1[r2 * 4 + i] = fmaf(bit1, delta2, sv1[r2 * 4 + i] + b1[i]);       \
        }                                                                      \
      }                                                                        \
    }                                                                          \
    /* ---- online softmax (row q: lanes l31, l31+32) ---- */                  \
    {                                                                          \
      float m8[8];                                                             \
      _Pragma("unroll")                                                        \
      for (int i = 0; i < 8; ++i)                                              \
        m8[i] = fmaxf(fmaxf(sv0[2 * i], sv0[2 * i + 1]),                       \
                      fmaxf(sv1[2 * i], sv1[2 * i + 1]));                      \
      float m4a = fmaxf(m8[0], m8[1]), m4b = fmaxf(m8[2], m8[3]);              \
      float m4c = fmaxf(m8[4], m8[5]), m4d = fmaxf(m8[6], m8[7]);              \
      float tmax = fmaxf(fmaxf(m4a, m4b), fmaxf(m4c, m4d));                    \
      tmax = fmaxf(tmax, __shfl_xor(tmax, 32));                                \
      if (!__all(tmax <= mrun + 4.0f)) {                                       \
        float mnew = fmaxf(mrun, tmax);                                        \
        float sc = __builtin_amdgcn_exp2f(mrun - mnew);                        \
        lrun *= sc;                                                            \
        Oc0 *= sc; Oc1 *= sc;                                                  \
        mrun = mnew;                                                           \
      }                                                                        \
      float s8[8];                                                             \
      _Pragma("unroll")                                                        \
      for (int i = 0; i < 8; ++i) {                                            \
        float p0 = __builtin_amdgcn_exp2f(sv0[2 * i] - mrun);                  \
        float p1 = __builtin_amdgcn_exp2f(sv0[2 * i + 1] - mrun);              \
        float p2 = __builtin_amdgcn_exp2f(sv1[2 * i] - mrun);                  \
        float p3 = __builtin_amdgcn_exp2f(sv1[2 * i + 1] - mrun);              \
        sv0[2 * i] = p0; sv0[2 * i + 1] = p1;                                  \
        sv1[2 * i] = p2; sv1[2 * i + 1] = p3;                                  \
        s8[i] = (p0 + p1) + (p2 + p3);                                         \
      }                                                                        \
      float s4a = s8[0] + s8[1], s4b = s8[2] + s8[3];                          \
      float s4c = s8[4] + s8[5], s4d = s8[6] + s8[7];                          \
      lrun += (s4a + s4b) + (s4c + s4d);   /* lane-partial; combined at end */ \
    }                                                                          \
    /* ---- pack P(T) -> pfA..pfD (pre-swapped B-frags) ---- */                \
    {                                                                          \
      unsigned a0 = cvtpk(sv0[0], sv0[1]),   a1 = cvtpk(sv0[2], sv0[3]);       \
      unsigned a2 = cvtpk(sv0[4], sv0[5]),   a3 = cvtpk(sv0[6], sv0[7]);       \
      plswap(a0, a2); plswap(a1, a3);                                          \
      pfA[0] = a0; pfA[1] = a1; pfA[2] = a2; pfA[3] = a3;                      \
      unsigned b0_ = cvtpk(sv0[8], sv0[9]),   b1_ = cvtpk(sv0[10], sv0[11]);   \
      unsigned b2_ = cvtpk(sv0[12], sv0[13]), b3_ = cvtpk(sv0[14], sv0[15]);   \
      plswap(b0_, b2_); plswap(b1_, b3_);                                      \
      pfB[0] = b0_; pfB[1] = b1_; pfB[2] = b2_; pfB[3] = b3_;                  \
      unsigned c0 = cvtpk(sv1[0], sv1[1]),   c1 = cvtpk(sv1[2], sv1[3]);       \
      unsigned c2 = cvtpk(sv1[4], sv1[5]),   c3 = cvtpk(sv1[6], sv1[7]);       \
      plswap(c0, c2); plswap(c1, c3);                                          \
      pfC[0] = c0; pfC[1] = c1; pfC[2] = c2; pfC[3] = c3;                      \
      unsigned d0 = cvtpk(sv1[8], sv1[9]),   d1 = cvtpk(sv1[10], sv1[11]);     \
      unsigned d2 = cvtpk(sv1[12], sv1[13]), d3 = cvtpk(sv1[14], sv1[15]);     \
      plswap(d0, d2); plswap(d1, d3);                                          \
      pfD[0] = d0; pfD[1] = d1; pfD[2] = d2; pfD[3] = d3;                      \
    }                                                                          \
    if (STG) {                                                                 \
      __syncthreads();                                                         \
      pwv = npwv;                                                              \
      if constexpr (USE_CM) {                                                  \
        _Pragma("unroll")                                                      \
        for (int q8 = 0; q8 < 8; ++q8) cmq[q8] = ncmq[q8];                     \
      }                                                                        \
    }                                                                          \
  }

  //      T  KB KSTG VRD VST PV STG
  BODY( 0, 0, 1,  0,  1, 0, 1)
  BODY( 1, 1, 0,  0,  2, 1, 1)
  BODY( 2, 0, 1,  1,  0, 1, 1)
  BODY( 3, 1, 0,  2,  1, 1, 1)
  BODY( 4, 0, 1,  0,  2, 1, 1)
  BODY( 5, 1, 0,  1,  0, 1, 1)
  BODY( 6, 0, 1,  2,  1, 1, 1)
  BODY( 7, 1, 0,  0,  2, 1, 1)
  BODY( 8, 0, 1,  1,  0, 1, 1)
  BODY( 9, 1, 0,  2,  1, 1, 1)
  BODY(10, 0, 1,  0,  2, 1, 1)
  BODY(11, 1, 0,  1,  0, 1, 1)
  BODY(12, 0, 1,  2,  1, 1, 1)
  BODY(13, 1, 0,  0,  2, 1, 1)
  BODY(14, 0, 1,  1,  0, 1, 1)
  BODY(15, 1, 0,  2,  0, 1, 0)
#undef BODY

  // ---- epilogue PV(15): V[15] lives in vbuf[15%3=0] ----
  __builtin_amdgcn_s_setprio(1);
  {
    bf16x8 p = __builtin_bit_cast(bf16x8, pfA);
    Oc0 = __builtin_amdgcn_mfma_f32_32x32x16_bf16(LDV(0, rb + co0), p, Oc0, 0, 0, 0);
    Oc1 = __builtin_amdgcn_mfma_f32_32x32x16_bf16(LDV(0, rb + 2048 + co0), p, Oc1, 0, 0, 0);
    p = __builtin_bit_cast(bf16x8, pfB);
    Oc0 = __builtin_amdgcn_mfma_f32_32x32x16_bf16(LDV(0, rb + co1), p, Oc0, 0, 0, 0);
    Oc1 = __builtin_amdgcn_mfma_f32_32x32x16_bf16(LDV(0, rb + 2048 + co1), p, Oc1, 0, 0, 0);
    p = __builtin_bit_cast(bf16x8, pfC);
    Oc0 = __builtin_amdgcn_mfma_f32_32x32x16_bf16(LDV(0, rb + co2), p, Oc0, 0, 0, 0);
    Oc1 = __builtin_amdgcn_mfma_f32_32x32x16_bf16(LDV(0, rb + 2048 + co2), p, Oc1, 0, 0, 0);
    p = __builtin_bit_cast(bf16x8, pfD);
    Oc0 = __builtin_amdgcn_mfma_f32_32x32x16_bf16(LDV(0, rb + co3), p, Oc0, 0, 0, 0);
    Oc1 = __builtin_amdgcn_mfma_f32_32x32x16_bf16(LDV(0, rb + 2048 + co3), p, Oc1, 0, 0, 0);
  }
  __builtin_amdgcn_s_setprio(0);
#undef LDK
#undef LDV

  // ---- epilogue: combine lane-partial lrun, /l, store O^T ----
  lrun += __shfl_xor(lrun, 32);
  float inv = 1.0f / lrun;
  float* orow = out + ((n * 1024 + l) * 16 + h) * 64;
#pragma unroll
  for (int r2 = 0; r2 < 4; ++r2) {
    float4 o;
    o.x = Oc0[4 * r2 + 0] * inv; o.y = Oc0[4 * r2 + 1] * inv;
    o.z = Oc0[4 * r2 + 2] * inv; o.w = Oc0[4 * r2 + 3] * inv;
    *(float4*)(orow + r2 * 8 + h4) = o;
    o.x = Oc1[4 * r2 + 0] * inv; o.y = Oc1[4 * r2 + 1] * inv;
    o.z = Oc1[4 * r2 + 2] * inv; o.w = Oc1[4 * r2 + 3] * inv;
    *(float4*)(orow + 32 + r2 * 8 + h4) = o;
  }
}

extern "C" void kernel_launch(void* const* d_in, const int* in_sizes, int n_in,
                              void* d_out, int out_size, void* d_ws, size_t ws_size,
                              hipStream_t stream) {
  const float* Q    = (const float*)d_in[0];
  const float* K    = (const float*)d_in[1];
  const float* V    = (const float*)d_in[2];
  const float* mask = (const float*)d_in[3];
  const float* klm  = (const float*)d_in[4];
  const float* ptab = (const float*)d_in[5];
  const int*   pos  = (const int*)d_in[6];
  float* out = (float*)d_out;

  char* ws = (char*)d_ws;
  unsigned int*   pospk = (unsigned int*)ws;                               // 512 KB
  unsigned short* Kp    = (unsigned short*)(ws + (1 << 19));               // 8 MB
  unsigned short* Vt    = (unsigned short*)(ws + (1 << 19) + (8 << 20));   // 8 MB
  unsigned short* CM    = (unsigned short*)(ws + (1 << 19) + (16 << 20));  // 8 MB
  const size_t need_cm = (size_t)(1 << 19) + (size_t)(24 << 20);
  const bool use_cm = ws_size >= need_cm;

  k_prep<<<18688, 256, 0, stream>>>(pos, pospk, K, Kp, V, Vt, mask, klm, CM,
                                    use_cm ? 1 : 0);
  if (use_cm) {
    k_attn<true><<<512, 256, 0, stream>>>(Q, mask, klm, ptab, pospk, Kp, Vt, CM, out);
  } else {
    k_attn<false><<<512, 256, 0, stream>>>(Q, mask, klm, ptab, pospk, Kp, Vt, nullptr, out);
  }
}